// Round 4
// baseline (440.681 us; speedup 1.0000x reference)
//
#include <hip/hip_runtime.h>
#include <cstdint>
#include <cstddef>

// ---------------- problem constants ----------------
#define B_   2
#define T_   2048
#define D_   2048
#define H_   16
#define DH_  128
#define DQ_  1024
#define DKV_ 512
#define DR_  64
#define M_   4096            // B_*T_
#define SCALE_ 0.07216878364870323f   // 1/sqrt(DH_+DR_)
#define SC2_   0.10412808709930322f   // SCALE_ * log2(e)
#define LN_BASE_ 13.122363377404328f  // ln(500000)

typedef unsigned short u16;
typedef __attribute__((ext_vector_type(8))) short short8;   // 8 bf16 (4 VGPRs)
typedef __attribute__((ext_vector_type(4))) float f32x4;    // 4 fp32 acc

__device__ __forceinline__ float b2f(u16 u) { return __uint_as_float(((uint32_t)u) << 16); }
__device__ __forceinline__ u16 f2b(float f) {            // RNE
    uint32_t x = __float_as_uint(f);
    return (u16)((x + 0x7fffu + ((x >> 16) & 1u)) >> 16);
}
__device__ __forceinline__ u16 f2b_fast(float f) {       // round-up-ties, 2 ops
    return (u16)((__float_as_uint(f) + 0x8000u) >> 16);
}

__device__ __forceinline__ void gload_lds16(const u16* src, u16* dst) {
    __builtin_amdgcn_global_load_lds(
        (const __attribute__((address_space(1))) uint32_t*)(uintptr_t)src,
        (__attribute__((address_space(3))) uint32_t*)(uintptr_t)dst, 16, 0, 0);
}

// ---- fused prep: 8 weight transposes (+cast) AND x fp32->bf16, one launch ---
struct TPack {
    const float* src[8];
    u16*         dst[8];
    int K[8];      // src rows
    int N[8];      // src cols (real)
    int ntx[8];    // tiles along out-row dim (covers padded N)
    int start[9];  // cumulative tile offsets
};

__global__ __launch_bounds__(256) void prep_k(TPack p, const float* __restrict__ x,
                                              u16* __restrict__ xb, int ntr) {
    const int bid = blockIdx.x;
    if (bid < ntr) {
        __shared__ float tile[32][33];
        int w = 0;
#pragma unroll
        for (int i = 1; i < 8; ++i) if (bid >= p.start[i]) w = i;
        const int lt = bid - p.start[w];
        const int bx = lt % p.ntx[w], by = lt / p.ntx[w];
        const float* in = p.src[w];
        u16* out = p.dst[w];
        const int K = p.K[w], N = p.N[w];
        const int k0 = by * 32, n0 = bx * 32;
        const int tx = threadIdx.x & 31, ty = threadIdx.x >> 5;  // 32x8
#pragma unroll
        for (int i = 0; i < 4; ++i) {
            int k = k0 + ty + i * 8;
            int n = n0 + tx;
            tile[ty + i * 8][tx] = (n < N) ? in[(size_t)k * N + n] : 0.f;
        }
        __syncthreads();
#pragma unroll
        for (int i = 0; i < 4; ++i) {
            int n = n0 + ty + i * 8;     // out row
            out[(size_t)n * K + k0 + tx] = f2b(tile[tx][ty + i * 8]);
        }
    } else {
        const int i = ((bid - ntr) * 256 + threadIdx.x) * 4;
        const float4 v = *(const float4*)(x + i);
        ushort4 o;
        o.x = f2b(v.x); o.y = f2b(v.y); o.z = f2b(v.z); o.w = f2b(v.w);
        *(ushort4*)(xb + i) = o;
    }
}

// ---------------- bf16 GEMM:  C(MxN) = A(MxK) @ B(KxN), Bt given as NxK ------
template <int OUT_BF16>
__global__ __launch_bounds__(256) void gemm_tn(const u16* __restrict__ A,
                                               const u16* __restrict__ Bt,
                                               void* __restrict__ Cv,
                                               int N, int K) {
    __shared__ __attribute__((aligned(16))) u16 lA[128 * 32];
    __shared__ __attribute__((aligned(16))) u16 lB[128 * 32];
    const int m0 = blockIdx.y * 128, n0 = blockIdx.x * 128;
    const int tid = threadIdx.x, wave = tid >> 6, lane = tid & 63;
    const int wm = (wave >> 1) * 64, wn = (wave & 1) * 64;
    const int r = lane & 15, kq = lane >> 4;

    f32x4 acc[4][4];
#pragma unroll
    for (int i = 0; i < 4; ++i)
#pragma unroll
        for (int j = 0; j < 4; ++j) acc[i][j] = (f32x4){0.f, 0.f, 0.f, 0.f};

    for (int kk = 0; kk < K; kk += 32) {
#pragma unroll
        for (int p = 0; p < 2; ++p) {
            const int c = p * 256 + wave * 64 + lane;          // 16B chunk id
            const u16* ga = A  + (size_t)(m0 + (c >> 2)) * K + kk + (c & 3) * 8;
            const u16* gb = Bt + (size_t)(n0 + (c >> 2)) * K + kk + (c & 3) * 8;
            u16* la = lA + (size_t)(p * 256 + wave * 64) * 8;  // wave-uniform base
            u16* lb = lB + (size_t)(p * 256 + wave * 64) * 8;
            gload_lds16(ga, la);
            gload_lds16(gb, lb);
        }
        __syncthreads();
        short8 av[4], bv[4];
#pragma unroll
        for (int mi = 0; mi < 4; ++mi)
            av[mi] = *(const short8*)&lA[(wm + mi * 16 + r) * 32 + kq * 8];
#pragma unroll
        for (int ni = 0; ni < 4; ++ni)
            bv[ni] = *(const short8*)&lB[(wn + ni * 16 + r) * 32 + kq * 8];
#pragma unroll
        for (int mi = 0; mi < 4; ++mi)
#pragma unroll
            for (int ni = 0; ni < 4; ++ni)
                acc[mi][ni] = __builtin_amdgcn_mfma_f32_16x16x32_bf16(
                    av[mi], bv[ni], acc[mi][ni], 0, 0, 0);
        __syncthreads();
    }
    const int r4 = (lane >> 4) * 4, cc = lane & 15;
#pragma unroll
    for (int mi = 0; mi < 4; ++mi)
#pragma unroll
        for (int ni = 0; ni < 4; ++ni)
#pragma unroll
            for (int i = 0; i < 4; ++i) {
                const int row = m0 + wm + mi * 16 + r4 + i;
                const int col = n0 + wn + ni * 16 + cc;
                const float v = acc[mi][ni][i];
                if (OUT_BF16) ((u16*)Cv)[(size_t)row * N + col] = f2b(v);
                else          ((float*)Cv)[(size_t)row * N + col] = v;
            }
}

// ---- two bf16 GEMMs in ONE launch (block-range routed): both M=4096 --------
__global__ __launch_bounds__(256) void gemm_pair(const u16* __restrict__ A0,
                                                 const u16* __restrict__ B0,
                                                 u16* __restrict__ C0, int N0, int K0,
                                                 const u16* __restrict__ A1,
                                                 const u16* __restrict__ B1,
                                                 u16* __restrict__ C1, int N1, int K1,
                                                 int nx0) {
    __shared__ __attribute__((aligned(16))) u16 lA[128 * 32];
    __shared__ __attribute__((aligned(16))) u16 lB[128 * 32];
    const int sel = (int)blockIdx.x >= nx0;
    const u16* A  = sel ? A1 : A0;
    const u16* Bt = sel ? B1 : B0;
    u16* Cv = sel ? C1 : C0;
    const int N = sel ? N1 : N0, K = sel ? K1 : K0;
    const int bx = sel ? (blockIdx.x - nx0) : blockIdx.x;
    const int m0 = blockIdx.y * 128, n0 = bx * 128;
    const int tid = threadIdx.x, wave = tid >> 6, lane = tid & 63;
    const int wm = (wave >> 1) * 64, wn = (wave & 1) * 64;
    const int r = lane & 15, kq = lane >> 4;

    f32x4 acc[4][4];
#pragma unroll
    for (int i = 0; i < 4; ++i)
#pragma unroll
        for (int j = 0; j < 4; ++j) acc[i][j] = (f32x4){0.f, 0.f, 0.f, 0.f};

    for (int kk = 0; kk < K; kk += 32) {
#pragma unroll
        for (int p = 0; p < 2; ++p) {
            const int c = p * 256 + wave * 64 + lane;
            const u16* ga = A  + (size_t)(m0 + (c >> 2)) * K + kk + (c & 3) * 8;
            const u16* gb = Bt + (size_t)(n0 + (c >> 2)) * K + kk + (c & 3) * 8;
            u16* la = lA + (size_t)(p * 256 + wave * 64) * 8;
            u16* lb = lB + (size_t)(p * 256 + wave * 64) * 8;
            gload_lds16(ga, la);
            gload_lds16(gb, lb);
        }
        __syncthreads();
        short8 av[4], bv[4];
#pragma unroll
        for (int mi = 0; mi < 4; ++mi)
            av[mi] = *(const short8*)&lA[(wm + mi * 16 + r) * 32 + kq * 8];
#pragma unroll
        for (int ni = 0; ni < 4; ++ni)
            bv[ni] = *(const short8*)&lB[(wn + ni * 16 + r) * 32 + kq * 8];
#pragma unroll
        for (int mi = 0; mi < 4; ++mi)
#pragma unroll
            for (int ni = 0; ni < 4; ++ni)
                acc[mi][ni] = __builtin_amdgcn_mfma_f32_16x16x32_bf16(
                    av[mi], bv[ni], acc[mi][ni], 0, 0, 0);
        __syncthreads();
    }
    const int r4 = (lane >> 4) * 4, cc = lane & 15;
#pragma unroll
    for (int mi = 0; mi < 4; ++mi)
#pragma unroll
        for (int ni = 0; ni < 4; ++ni)
#pragma unroll
            for (int i = 0; i < 4; ++i) {
                const int row = m0 + wm + mi * 16 + r4 + i;
                const int col = n0 + wn + ni * 16 + cc;
                Cv[(size_t)row * N + col] = f2b(acc[mi][ni][i]);
            }
}

// ---- SHADOW: 256x256 8-phase pipelined GEMM (T2 swizzle + T3/T4 counted
// vmcnt + T5 setprio). This round it runs into P3 BEFORE the real gemm_pair
// (which fully overwrites P3), so it cannot affect correctness — it exists to
// measure the 8-phase structure's duration/conflicts at our shapes.
#define S_BM 256
#define S_BN 256
#define S_BK 64

__global__ __launch_bounds__(512, 1) void gemm256_k(const u16* __restrict__ A,
                                                    const u16* __restrict__ Bt,
                                                    u16* __restrict__ C,
                                                    int N, int K) {
    __shared__ __attribute__((aligned(16))) u16 sA[2][S_BM * S_BK]; // 2 x 32 KB
    __shared__ __attribute__((aligned(16))) u16 sB[2][S_BN * S_BK]; // 2 x 32 KB
    const int m0 = blockIdx.y * S_BM, n0 = blockIdx.x * S_BN;
    const int tid = threadIdx.x, lane = tid & 63;
    const int wave = tid >> 6;
    const int wm = wave >> 2, wn = wave & 3;          // 2 x 4 wave grid
    const int r = lane & 15, kq = lane >> 4;

    // staging plan: chunk c = is*512 + tid ; row = c>>3 (0..255), c16 = c&7.
    // swizzle (T2, G4-XOR): LDS linear dest; global source chunk = c16^(row&7).
    const u16* gA[4]; const u16* gB[4]; int dOf[4];
#pragma unroll
    for (int is = 0; is < 4; ++is) {
        const int c = is * 512 + tid;
        const int row = c >> 3, c16 = c & 7;
        gA[is] = A  + (size_t)(m0 + row) * K + ((c16 ^ (row & 7)) * 8);
        gB[is] = Bt + (size_t)(n0 + row) * K + ((c16 ^ (row & 7)) * 8);
        dOf[is] = c * 8;
    }

    f32x4 acc[8][4];
#pragma unroll
    for (int i = 0; i < 8; ++i)
#pragma unroll
        for (int j = 0; j < 4; ++j) acc[i][j] = (f32x4){0.f, 0.f, 0.f, 0.f};

    const int NKT = K >> 6;

    // stage one half-tile (2 loads/thread): arr=0 -> A, arr=1 -> B
    auto STG = [&](int arr, int half, int bs, int kk) {
        u16* dst = arr ? (u16*)sB[bs] : (u16*)sA[bs];
        const u16** g = arr ? gB : gA;
#pragma unroll
        for (int is = half * 2; is < half * 2 + 2; ++is)
            gload_lds16(g[is] + kk, dst + dOf[is]);
    };

    // prologue: all 4 halves of kt=0 into buf 0
    STG(0, 0, 0, 0); STG(0, 1, 0, 0); STG(1, 0, 0, 0); STG(1, 1, 0, 0);

    short8 af[4][2], bf[2][2];
    for (int kt = 0; kt < NKT; ++kt) {
        const int cur = kt & 1;
        const int kk = (kt + 1) * 64;
        const int pf = (kt + 1 < NKT);
        const u16* cA = sA[cur];
        const u16* cB = sB[cur];

        // swizzled fragment readers
        auto lda = [&](int row, int g) -> short8 {
            return *(const short8*)&cA[row * 64 + ((g ^ (row & 7)) * 8)];
        };
        auto ldb = [&](int row, int g) -> short8 {
            return *(const short8*)&cB[row * 64 + ((g ^ (row & 7)) * 8)];
        };

#pragma unroll
        for (int ph = 0; ph < 4; ++ph) {
            // phase -> (M-half, N-half); order reuses af across p0/p1, p2/p3
            const int mh = ph >> 1;
            const int nh = (ph == 1 || ph == 2) ? 1 : 0;
            // stage one half-tile of kt+1: p0:Ah0 p1:Ah1 p2:Bh0 p3:Bh1
            if (pf) STG(ph >> 1, ph & 1, cur ^ 1, kk);
            if (ph == 0) {
                if (pf) asm volatile("s_waitcnt vmcnt(2)" ::: "memory");
                else    asm volatile("s_waitcnt vmcnt(0)" ::: "memory");
            }
            __builtin_amdgcn_s_barrier();
            asm volatile("" ::: "memory");
            // ds-load frags for this quadrant (af reused on odd phases)
            if (!(ph & 1)) {
#pragma unroll
                for (int mi = 0; mi < 4; ++mi)
#pragma unroll
                    for (int ks = 0; ks < 2; ++ks)
                        af[mi][ks] = lda(wm * 128 + mh * 64 + mi * 16 + r, ks * 4 + kq);
            }
#pragma unroll
            for (int ni = 0; ni < 2; ++ni)
#pragma unroll
                for (int ks = 0; ks < 2; ++ks)
                    bf[ni][ks] = ldb(wn * 64 + nh * 32 + ni * 16 + r, ks * 4 + kq);
            __builtin_amdgcn_s_setprio(1);
#pragma unroll
            for (int ks = 0; ks < 2; ++ks)
#pragma unroll
                for (int mi = 0; mi < 4; ++mi)
#pragma unroll
                    for (int ni = 0; ni < 2; ++ni)
                        acc[mh * 4 + mi][nh * 2 + ni] =
                            __builtin_amdgcn_mfma_f32_16x16x32_bf16(
                                af[mi][ks], bf[ni][ks],
                                acc[mh * 4 + mi][nh * 2 + ni], 0, 0, 0);
            __builtin_amdgcn_s_setprio(0);
            asm volatile("" ::: "memory");
            __builtin_amdgcn_s_barrier();
            asm volatile("" ::: "memory");
        }
    }

    // epilogue (bounds-clamped for shadow safety)
    const int r4c = kq * 4, cc = lane & 15;
#pragma unroll
    for (int mf = 0; mf < 8; ++mf)
#pragma unroll
        for (int nf = 0; nf < 4; ++nf)
#pragma unroll
            for (int i = 0; i < 4; ++i) {
                const int row = m0 + wm * 128 + mf * 16 + r4c + i;
                const int col = n0 + wn * 64 + nf * 16 + cc;
                if (row < M_ && col < N)
                    C[(size_t)row * N + col] = f2b(acc[mf][nf][i]);
            }
}

// ---- fused per-row ops on P1: rmsnorm(q), rmsnorm(kv), rope_k — one launch --
__global__ __launch_bounds__(256) void normrope_k(const u16* __restrict__ P1,
                                                  const float* __restrict__ qnw,
                                                  const float* __restrict__ kvnw,
                                                  u16* __restrict__ cQb,
                                                  u16* __restrict__ cKVb,
                                                  u16* __restrict__ kRb) {
    const int which = blockIdx.y;
    if (which < 2) {
        const int row = blockIdx.x;
        const int N = which ? 512 : 1024;
        const int off = which ? 1024 : 0;
        const float* w = which ? kvnw : qnw;
        u16* outp = which ? cKVb : cQb;
        const u16* src = P1 + (size_t)row * 1664 + off;
        const int j = threadIdx.x * 4;
        float v[4] = {0.f, 0.f, 0.f, 0.f};
        if (j < N) {
            ushort4 u = *(const ushort4*)(src + j);
            v[0] = b2f(u.x); v[1] = b2f(u.y); v[2] = b2f(u.z); v[3] = b2f(u.w);
        }
        float ss = v[0]*v[0] + v[1]*v[1] + v[2]*v[2] + v[3]*v[3];
#pragma unroll
        for (int offc = 32; offc; offc >>= 1) ss += __shfl_down(ss, offc);
        __shared__ float red[4];
        const int wave = threadIdx.x >> 6, lane = threadIdx.x & 63;
        if (lane == 0) red[wave] = ss;
        __syncthreads();
        const float tot = red[0] + red[1] + red[2] + red[3];
        const float sc = rsqrtf(tot / (float)N + 1e-6f);
        if (j < N) {
            ushort4 o;
            o.x = f2b(v[0] * sc * w[j]);
            o.y = f2b(v[1] * sc * w[j + 1]);
            o.z = f2b(v[2] * sc * w[j + 2]);
            o.w = f2b(v[3] * sc * w[j + 3]);
            *(ushort4*)(outp + (size_t)row * N + j) = o;
        }
    } else {
        // rope_k: 4 rows per block, 64 lanes each
        if (blockIdx.x >= 1024) return;
        const int row = blockIdx.x * 4 + (threadIdx.x >> 6);
        const int j = threadIdx.x & 63;
        const int t = row & (T_ - 1);
        const int i = j & 31;
        const float invf = __expf(-LN_BASE_ * (float)(2 * i) * (1.0f / 64.0f));
        const float ang = (float)t * invf;
        const float c = cosf(ang), s = sinf(ang);
        const u16* src = P1 + (size_t)row * 1664 + 1536;
        const float v = b2f(src[j]);
        const float rot = (j < 32) ? -b2f(src[j + 32]) : b2f(src[j - 32]);
        kRb[(size_t)row * 64 + j] = f2b(v * c + rot * s);
    }
}

// ---- V^T transpose only (RoPE-q now fused into attn Q-load) ----------------
__global__ __launch_bounds__(256) void vtrans_k(const u16* __restrict__ P3,
                                                u16* __restrict__ Vt) {
    __shared__ u16 tile[64][72];
    const int tt = blockIdx.x;           // 0..2047
    const int b = tt >> 10;
    const int rem = tt & 1023;
    const int by = rem >> 5, bx = rem & 31;
    const int t0 = by * 64, c0 = bx * 64;
    const int tid = threadIdx.x;
    const int rr2 = tid >> 3;        // 0..31
    const int c8 = tid & 7;          // 16B chunk within 64
#pragma unroll
    for (int p = 0; p < 2; ++p) {
        const int row = p * 32 + rr2;
        *(uint4*)&tile[row][c8 * 8] =
            *(const uint4*)(P3 + (size_t)(b * T_ + t0 + row) * 4096 + 2048 + c0 + c8 * 8);
    }
    __syncthreads();
#pragma unroll
    for (int p = 0; p < 2; ++p) {
        const int c = p * 32 + rr2;
        u16 tmp[8];
#pragma unroll
        for (int j = 0; j < 8; ++j) tmp[j] = tile[c8 * 8 + j][c];
        *(uint4*)(Vt + ((size_t)b * 2048 + c0 + c) * 2048 + t0 + c8 * 8) = *(uint4*)tmp;
    }
}

// ---------------- MFMA flash attention (causal, d=192, dv=128) --------------
// R3 T3/T4 pipelined structure (proven: 94.4us) + R4: T5 setprio around MFMA
// clusters; RoPE(q) fused in-register at Q-load (drops qRb dependency).
#define ABQ  128
#define ABK  64
#define NW   8
#define KSTR 200   // sK row stride u16 (25 chunks x 8)
#define VSTR 72    // sV row stride u16 (9 chunks x 8)
#define PSTR 72    // sP row stride u16
#define VOFF 12800 // u16 offset of V region inside a KV buffer (25*512)
#define KVSZ 22016 // u16 per KV buffer (43*512)
#define QSTRIDE 3072   // P2 row stride (qC cols 0..2047, qR_raw 2048..3071)
#define KSTRIDE 4096   // P3 row stride (kC cols 0..2047)

__global__ __launch_bounds__(512, 1) void attn_mfma_k(
    const u16* __restrict__ qC,
    const u16* __restrict__ kC, const u16* __restrict__ kR,
    const u16* __restrict__ Vt, u16* __restrict__ outp)
{
    __shared__ __attribute__((aligned(16))) u16 sKV[2][KVSZ];   // 2 x 43 KB
    __shared__ __attribute__((aligned(16))) u16 sP[NW * 16 * PSTR]; // 18 KB

    const int h = blockIdx.x, b = blockIdx.z;                      // x=h: XCD cluster
    const int qb = b ? (15 - (int)blockIdx.y) : (int)blockIdx.y;   // causal balance
    const int q0 = qb * ABQ;
    const int tid = threadIdx.x, wave = tid >> 6, lane = tid & 63;
    const int r = lane & 15, kq = lane >> 4, r4 = kq * 4;
    const int wq = wave * 16;

    // ---- per-wave staging plan: 6 slots each, precomputed bases
    const u16* gsrc[6]; int gstep[6]; int doff[6];
#pragma unroll
    for (int j = 0; j < 6; ++j) {
        const int i = wave + NW * j;              // 0..47
        const int slot = (i < 43) ? i : (i - 43); // pad slots dup K slots 0..4
        if (slot < 25) {                          // K chunk
            const int s = slot * 64 + lane;
            const int rr2 = s / 25;
            int cc = s - rr2 * 25;
            if (cc > 23) cc = 0;                  // pad col: harmless dup
            if (cc < 16) {
                gsrc[j] = kC + (size_t)(b * T_ + rr2) * KSTRIDE + h * 128 + cc * 8;
                gstep[j] = ABK * KSTRIDE;
            } else {
                gsrc[j] = kR + (size_t)(b * T_ + rr2) * 64 + (cc - 16) * 8;
                gstep[j] = ABK * 64;
            }
            doff[j] = slot * 512;
        } else {                                  // V chunk
            const int sl = slot - 25;             // 0..17
            const int s = sl * 64 + lane;
            const int rr2 = s / 9;
            int cc = s - rr2 * 9;
            if (cc > 7) cc = 0;                   // pad col
            gsrc[j] = Vt + ((size_t)(b * H_ + h) * 128 + rr2) * T_ + cc * 8;
            gstep[j] = ABK;
            doff[j] = VOFF + sl * 512;
        }
    }

    // ---- Q fragments in registers; RoPE(q) fused for the rope dims
    short8 qf[6];
    {
        const int t = q0 + wq + r;
        const u16* qcrow = qC + (size_t)(b * T_ + t) * QSTRIDE + h * 128 + kq * 8;
#pragma unroll
        for (int kc = 0; kc < 4; ++kc) qf[kc] = *(const short8*)(qcrow + kc * 32);
        const u16* qrraw = qC + (size_t)(b * T_ + t) * QSTRIDE + 2048 + h * 64 + kq * 8;
        const short8 q0v = *(const short8*)(qrraw);
        const short8 q1v = *(const short8*)(qrraw + 32);
        short8 o0, o1;
#pragma unroll
        for (int j = 0; j < 8; ++j) {
            const int i = kq * 8 + j;             // dim mod 32 (same for both halves)
            const float invf = __expf(-LN_BASE_ * (float)(2 * i) * (1.0f / 64.0f));
            const float ang = (float)t * invf;
            const float cs = cosf(ang), sn = sinf(ang);
            const float a = b2f((u16)q0v[j]), bb = b2f((u16)q1v[j]);
            o0[j] = (short)f2b(a * cs - bb * sn);
            o1[j] = (short)f2b(bb * cs + a * sn);
        }
        qf[4] = o0; qf[5] = o1;
    }

    f32x4 Oa[8];
#pragma unroll
    for (int nt = 0; nt < 8; ++nt) Oa[nt] = (f32x4){0.f, 0.f, 0.f, 0.f};
    float Lrow[4] = {0.f, 0.f, 0.f, 0.f};

    u16* myP = sP + wave * 16 * PSTR;

    auto STAGE = [&](int kt2, int bs) {
        u16* dst = &sKV[bs][0];
#pragma unroll
        for (int j = 0; j < 6; ++j)
            gload_lds16(gsrc[j] + (size_t)kt2 * (size_t)gstep[j], dst + doff[j]);
    };

    const int nkt = 2 * qb + 2;
    STAGE(0, 0);
    for (int kt = 0; kt < nkt; ++kt) {
        const int cur = kt & 1;
        if (kt + 1 < nkt) STAGE(kt + 1, cur ^ 1);
        if (kt == 0 || kt + 1 >= nkt) {
            asm volatile("s_waitcnt vmcnt(0)" ::: "memory");
        } else {
            asm volatile("s_waitcnt vmcnt(6)" ::: "memory");
        }
        __builtin_amdgcn_s_barrier();
        asm volatile("" ::: "memory");

        const u16* cK = &sKV[cur][0];
        const u16* cV = &sKV[cur][VOFF];
        const int k0 = kt * ABK;

        // ---- S = Q K^T  (24 MFMA/wave)
        f32x4 Sa[4];
#pragma unroll
        for (int nt = 0; nt < 4; ++nt) Sa[nt] = (f32x4){0.f, 0.f, 0.f, 0.f};
        __builtin_amdgcn_s_setprio(1);
#pragma unroll
        for (int kc = 0; kc < 6; ++kc) {
            short8 kf[4];
#pragma unroll
            for (int nt = 0; nt < 4; ++nt)
                kf[nt] = *(const short8*)&cK[(nt * 16 + r) * KSTR + (kc * 4 + kq) * 8];
#pragma unroll
            for (int nt = 0; nt < 4; ++nt)
                Sa[nt] = __builtin_amdgcn_mfma_f32_16x16x32_bf16(
                    qf[kc], kf[nt], Sa[nt], 0, 0, 0);
        }
        __builtin_amdgcn_s_setprio(0);

        // ---- no-max softmax: p = exp2(S*SC2); wave-uniform mask split
        if (kt < nkt - 2) {
#pragma unroll
            for (int i = 0; i < 4; ++i) {
                float sm = 0.f;
#pragma unroll
                for (int nt = 0; nt < 4; ++nt) {
                    const float p = exp2f(Sa[nt][i] * SC2_);
                    sm += p;
                    myP[(r4 + i) * PSTR + nt * 16 + r] = f2b_fast(p);
                }
                Lrow[i] += sm;
            }
        } else {
#pragma unroll
            for (int i = 0; i < 4; ++i) {
                const int grow = q0 + wq + r4 + i;
                float sm = 0.f;
#pragma unroll
                for (int nt = 0; nt < 4; ++nt) {
                    float p = exp2f(Sa[nt][i] * SC2_);
                    p = (k0 + nt * 16 + r > grow) ? 0.f : p;
                    sm += p;
                    myP[(r4 + i) * PSTR + nt * 16 + r] = f2b_fast(p);
                }
                Lrow[i] += sm;
            }
        }

        // ---- O += P V  (P wave-local; same-wave DS order via lgkmcnt)
        __builtin_amdgcn_s_setprio(1);
#pragma unroll
        for (int kc2 = 0; kc2 < 2; ++kc2) {
            const short8 pf = *(const short8*)&myP[r * PSTR + (kc2 * 4 + kq) * 8];
#pragma unroll
            for (int nt = 0; nt < 8; ++nt) {
                const short8 vf = *(const short8*)&cV[(nt * 16 + r) * VSTR + (kc2 * 4 + kq) * 8];
                Oa[nt] = __builtin_amdgcn_mfma_f32_16x16x32_bf16(
                    pf, vf, Oa[nt], 0, 0, 0);
            }
        }
        __builtin_amdgcn_s_setprio(0);

        // release: all waves done reading buf[cur] before kt+1 stages into it
        asm volatile("" ::: "memory");
        __builtin_amdgcn_s_barrier();
        asm volatile("" ::: "memory");
    }

    // ---- epilogue: reduce L across the 16 lanes of each quad-group, O /= L
#pragma unroll
    for (int i = 0; i < 4; ++i) {
        float L = Lrow[i];
        L += __shfl_xor(L, 1);
        L += __shfl_xor(L, 2);
        L += __shfl_xor(L, 4);
        L += __shfl_xor(L, 8);
        const float inv = 1.0f / L;
        const int t = q0 + wq + r4 + i;
        u16* orow = outp + (size_t)(b * T_ + t) * 2048 + h * 128;
#pragma unroll
        for (int nt = 0; nt < 8; ++nt)
            orow[nt * 16 + r] = f2b(Oa[nt][i] * inv);
    }
}

// ---------------- host side -------------------------------------------------
// Workspace plan: 139.46 MB (proven safe). U1 time-shared: P1 then attn_out.
// Vt reuses xb. 8 dispatches this round (incl. SHADOW gemm256_k into P3,
// fully overwritten by real gemm_pair -> correctness unaffected).
extern "C" void kernel_launch(void* const* d_in, const int* in_sizes, int n_in,
                              void* d_out, int out_size, void* d_ws, size_t ws_size,
                              hipStream_t stream) {
    (void)in_sizes; (void)n_in; (void)out_size; (void)ws_size;
    const float* x     = (const float*)d_in[0];
    const float* W_DQ  = (const float*)d_in[1];
    const float* W_UQ  = (const float*)d_in[2];
    const float* W_QR  = (const float*)d_in[3];
    const float* W_DKV = (const float*)d_in[4];
    const float* W_UK  = (const float*)d_in[5];
    const float* W_UV  = (const float*)d_in[6];
    const float* W_KR  = (const float*)d_in[7];
    const float* W_O   = (const float*)d_in[8];
    const float* qnw   = (const float*)d_in[9];
    const float* kvnw  = (const float*)d_in[10];
    float* out = (float*)d_out;   // fp32 output per reference dtype

    char* base = (char*)d_ws;
    size_t o = 0;
    auto alloc = [&](size_t bytes) {
        char* r = base + o;
        o += (bytes + 255) & ~(size_t)255;
        return r;
    };
    u16* WT1  = (u16*)alloc((size_t)1664 * 2048 * 2);
    u16* WT2  = (u16*)alloc((size_t)3072 * 1024 * 2);
    u16* WT3  = (u16*)alloc((size_t)4096 * 512 * 2);
    u16* WT_O = (u16*)alloc((size_t)2048 * 2048 * 2);
    u16* xb   = (u16*)alloc((size_t)M_ * 2048 * 2);    // x bf16; later Vt
    u16* U1   = (u16*)alloc((size_t)M_ * 2048 * 2);    // P1 then attn_out
    u16* P2   = (u16*)alloc((size_t)M_ * 3072 * 2);    // [qC | qR_raw]
    u16* P3   = (u16*)alloc((size_t)M_ * 4096 * 2);    // [kC | vC]
    u16* cQb  = (u16*)alloc((size_t)M_ * 1024 * 2);
    u16* cKVb = (u16*)alloc((size_t)M_ * 512 * 2);
    u16* qRb  = (u16*)alloc((size_t)M_ * 1024 * 2);    // (unused this round)
    u16* kRb  = (u16*)alloc((size_t)M_ * 64 * 2);
    (void)qRb;
    u16* P1       = U1;
    u16* attn_out = U1;
    u16* Vt       = xb;

    // ---- dispatch 1: all 8 weight transposes + x cast
    TPack tp;
    const float* srcs[8] = {W_DQ, W_DKV, W_KR, W_UQ, W_QR, W_UK, W_UV, W_O};
    u16* dsts[8] = {WT1, WT1 + (size_t)1024*2048, WT1 + (size_t)1536*2048,
                    WT2, WT2 + (size_t)2048*1024,
                    WT3, WT3 + (size_t)2048*512, WT_O};
    const int Ks[8]   = {2048, 2048, 2048, 1024, 1024, 512, 512, 2048};
    const int Ns[8]   = {1024,  512,   64, 2048, 1024, 2048, 2048, 2048};
    const int ntxs[8] = {  32,   16,    4,   64,   32,   64,   64,   64};
    int cum = 0;
    for (int i = 0; i < 8; ++i) {
        tp.src[i] = srcs[i]; tp.dst[i] = dsts[i];
        tp.K[i] = Ks[i]; tp.N[i] = Ns[i]; tp.ntx[i] = ntxs[i];
        tp.start[i] = cum;
        cum += ntxs[i] * (Ks[i] / 32);
    }
    tp.start[8] = cum;   // 12544 transpose tiles
    const int ncast = (M_ * D_) / 1024;   // 8192 cast blocks
    prep_k<<<cum + ncast, 256, 0, stream>>>(tp, x, xb, cum);

    // ---- dispatch 2: proj1: x @ [W_DQ | W_DKV | W_KR] -> P1 (M x 1664)
    gemm_tn<1><<<dim3(1664/128, M_/128), 256, 0, stream>>>(xb, WT1, (void*)P1, 1664, 2048);

    // ---- dispatch 3: fused rmsnorm(q) + rmsnorm(kv) + rope_k
    normrope_k<<<dim3(M_, 3), 256, 0, stream>>>(P1, qnw, kvnw, cQb, cKVb, kRb);

    // ---- dispatch 3.5 (SHADOW): 8-phase 256^2 GEMM probe, pair-b shape.
    // Writes P3; real gemm_pair below fully overwrites P3 -> zero correctness
    // impact. Exists to measure the 8-phase structure on this chip/shape.
    gemm256_k<<<dim3(4096/256, 4096/256), 512, 0, stream>>>(cKVb, WT3, P3, 4096, 512);

    // ---- dispatch 4: proj2a (cQ @ [W_UQ|W_QR] -> P2) + proj2b (cKV @ [W_UK|W_UV] -> P3)
    gemm_pair<<<dim3(3072/128 + 4096/128, M_/128), 256, 0, stream>>>(
        cQb,  WT2, P2, 3072, 1024,
        cKVb, WT3, P3, 4096, 512,
        3072/128);

    // ---- dispatch 5: V^T transpose only (RoPE-q fused into attn)
    vtrans_k<<<2048, 256, 0, stream>>>(P3, Vt);

    // ---- dispatch 6: attention — 512 thr/block; grid x=h (XCD), y=qb, z=b
    attn_mfma_k<<<dim3(H_, T_/ABQ, B_), 512, 0, stream>>>(P2, P3, kRb, Vt, attn_out);

    // ---- dispatch 7: output projection -> d_out (fp32)
    gemm_tn<0><<<dim3(2048/128, M_/128), 256, 0, stream>>>(attn_out, WT_O, (void*)out, 2048, 2048);
}

// Round 5
// 416.173 us; speedup vs baseline: 1.0589x; 1.0589x over previous
//
#include <hip/hip_runtime.h>
#include <cstdint>
#include <cstddef>

// ---------------- problem constants ----------------
#define B_   2
#define T_   2048
#define D_   2048
#define H_   16
#define DH_  128
#define DQ_  1024
#define DKV_ 512
#define DR_  64
#define M_   4096            // B_*T_
#define SCALE_ 0.07216878364870323f   // 1/sqrt(DH_+DR_)
#define SC2_   0.10412808709930322f   // SCALE_ * log2(e)
#define LN_BASE_ 13.122363377404328f  // ln(500000)

typedef unsigned short u16;
typedef __attribute__((ext_vector_type(8))) short short8;   // 8 bf16 (4 VGPRs)
typedef __attribute__((ext_vector_type(4))) float f32x4;    // 4 fp32 acc

__device__ __forceinline__ float b2f(u16 u) { return __uint_as_float(((uint32_t)u) << 16); }
__device__ __forceinline__ u16 f2b(float f) {            // RNE
    uint32_t x = __float_as_uint(f);
    return (u16)((x + 0x7fffu + ((x >> 16) & 1u)) >> 16);
}
__device__ __forceinline__ u16 f2b_fast(float f) {       // round-up-ties, 2 ops
    return (u16)((__float_as_uint(f) + 0x8000u) >> 16);
}

__device__ __forceinline__ void gload_lds16(const u16* src, u16* dst) {
    __builtin_amdgcn_global_load_lds(
        (const __attribute__((address_space(1))) uint32_t*)(uintptr_t)src,
        (__attribute__((address_space(3))) uint32_t*)(uintptr_t)dst, 16, 0, 0);
}

// ---- fused prep: 8 weight transposes (+cast) AND x fp32->bf16, one launch ---
struct TPack {
    const float* src[8];
    u16*         dst[8];
    int K[8];      // src rows
    int N[8];      // src cols (real)
    int ntx[8];    // tiles along out-row dim (covers padded N)
    int start[9];  // cumulative tile offsets
};

__global__ __launch_bounds__(256) void prep_k(TPack p, const float* __restrict__ x,
                                              u16* __restrict__ xb, int ntr) {
    const int bid = blockIdx.x;
    if (bid < ntr) {
        __shared__ float tile[32][33];
        int w = 0;
#pragma unroll
        for (int i = 1; i < 8; ++i) if (bid >= p.start[i]) w = i;
        const int lt = bid - p.start[w];
        const int bx = lt % p.ntx[w], by = lt / p.ntx[w];
        const float* in = p.src[w];
        u16* out = p.dst[w];
        const int K = p.K[w], N = p.N[w];
        const int k0 = by * 32, n0 = bx * 32;
        const int tx = threadIdx.x & 31, ty = threadIdx.x >> 5;  // 32x8
#pragma unroll
        for (int i = 0; i < 4; ++i) {
            int k = k0 + ty + i * 8;
            int n = n0 + tx;
            tile[ty + i * 8][tx] = (n < N) ? in[(size_t)k * N + n] : 0.f;
        }
        __syncthreads();
#pragma unroll
        for (int i = 0; i < 4; ++i) {
            int n = n0 + ty + i * 8;     // out row
            out[(size_t)n * K + k0 + tx] = f2b(tile[tx][ty + i * 8]);
        }
    } else {
        const int i = ((bid - ntr) * 256 + threadIdx.x) * 4;
        const float4 v = *(const float4*)(x + i);
        ushort4 o;
        o.x = f2b(v.x); o.y = f2b(v.y); o.z = f2b(v.z); o.w = f2b(v.w);
        *(ushort4*)(xb + i) = o;
    }
}

// ---------------- bf16 GEMM:  C(MxN) = A(MxK) @ B(KxN), Bt given as NxK ------
template <int OUT_BF16>
__global__ __launch_bounds__(256) void gemm_tn(const u16* __restrict__ A,
                                               const u16* __restrict__ Bt,
                                               void* __restrict__ Cv,
                                               int N, int K) {
    __shared__ __attribute__((aligned(16))) u16 lA[128 * 32];
    __shared__ __attribute__((aligned(16))) u16 lB[128 * 32];
    const int m0 = blockIdx.y * 128, n0 = blockIdx.x * 128;
    const int tid = threadIdx.x, wave = tid >> 6, lane = tid & 63;
    const int wm = (wave >> 1) * 64, wn = (wave & 1) * 64;
    const int r = lane & 15, kq = lane >> 4;

    f32x4 acc[4][4];
#pragma unroll
    for (int i = 0; i < 4; ++i)
#pragma unroll
        for (int j = 0; j < 4; ++j) acc[i][j] = (f32x4){0.f, 0.f, 0.f, 0.f};

    for (int kk = 0; kk < K; kk += 32) {
#pragma unroll
        for (int p = 0; p < 2; ++p) {
            const int c = p * 256 + wave * 64 + lane;          // 16B chunk id
            const u16* ga = A  + (size_t)(m0 + (c >> 2)) * K + kk + (c & 3) * 8;
            const u16* gb = Bt + (size_t)(n0 + (c >> 2)) * K + kk + (c & 3) * 8;
            u16* la = lA + (size_t)(p * 256 + wave * 64) * 8;  // wave-uniform base
            u16* lb = lB + (size_t)(p * 256 + wave * 64) * 8;
            gload_lds16(ga, la);
            gload_lds16(gb, lb);
        }
        __syncthreads();
        short8 av[4], bv[4];
#pragma unroll
        for (int mi = 0; mi < 4; ++mi)
            av[mi] = *(const short8*)&lA[(wm + mi * 16 + r) * 32 + kq * 8];
#pragma unroll
        for (int ni = 0; ni < 4; ++ni)
            bv[ni] = *(const short8*)&lB[(wn + ni * 16 + r) * 32 + kq * 8];
#pragma unroll
        for (int mi = 0; mi < 4; ++mi)
#pragma unroll
            for (int ni = 0; ni < 4; ++ni)
                acc[mi][ni] = __builtin_amdgcn_mfma_f32_16x16x32_bf16(
                    av[mi], bv[ni], acc[mi][ni], 0, 0, 0);
        __syncthreads();
    }
    const int r4 = (lane >> 4) * 4, cc = lane & 15;
#pragma unroll
    for (int mi = 0; mi < 4; ++mi)
#pragma unroll
        for (int ni = 0; ni < 4; ++ni)
#pragma unroll
            for (int i = 0; i < 4; ++i) {
                const int row = m0 + wm + mi * 16 + r4 + i;
                const int col = n0 + wn + ni * 16 + cc;
                const float v = acc[mi][ni][i];
                if (OUT_BF16) ((u16*)Cv)[(size_t)row * N + col] = f2b(v);
                else          ((float*)Cv)[(size_t)row * N + col] = v;
            }
}

// ---- 256x256 8-wave pipelined GEMM (T2 swizzle + T3/T4 counted vmcnt) ------
// PROMOTED this round: computes proj2b (cKV @ [W_UK|W_UV] -> P3) for real, so
// the harness verifies it. 4 compute phases/K-tile, 2 staging loads/phase,
// counted vmcnt(2) acquire once per K-tile, trailing barrier prevents
// prefetch-overwrite of a buffer still being read.
#define S_BM 256
#define S_BN 256
#define S_BK 64

__global__ __launch_bounds__(512, 1) void gemm256_k(const u16* __restrict__ A,
                                                    const u16* __restrict__ Bt,
                                                    u16* __restrict__ C,
                                                    int N, int K) {
    __shared__ __attribute__((aligned(16))) u16 sA[2][S_BM * S_BK]; // 2 x 32 KB
    __shared__ __attribute__((aligned(16))) u16 sB[2][S_BN * S_BK]; // 2 x 32 KB
    const int m0 = blockIdx.y * S_BM, n0 = blockIdx.x * S_BN;
    const int tid = threadIdx.x, lane = tid & 63;
    const int wave = tid >> 6;
    const int wm = wave >> 2, wn = wave & 3;          // 2 x 4 wave grid
    const int r = lane & 15, kq = lane >> 4;

    // staging plan: chunk c = is*512 + tid ; row = c>>3 (0..255), c16 = c&7.
    // swizzle (T2, G4-XOR): LDS linear dest; global source chunk = c16^(row&7).
    const u16* gA[4]; const u16* gB[4]; int dOf[4];
#pragma unroll
    for (int is = 0; is < 4; ++is) {
        const int c = is * 512 + tid;
        const int row = c >> 3, c16 = c & 7;
        gA[is] = A  + (size_t)(m0 + row) * K + ((c16 ^ (row & 7)) * 8);
        gB[is] = Bt + (size_t)(n0 + row) * K + ((c16 ^ (row & 7)) * 8);
        dOf[is] = c * 8;
    }

    f32x4 acc[8][4];
#pragma unroll
    for (int i = 0; i < 8; ++i)
#pragma unroll
        for (int j = 0; j < 4; ++j) acc[i][j] = (f32x4){0.f, 0.f, 0.f, 0.f};

    const int NKT = K >> 6;

    // stage one half-tile (2 loads/thread): arr=0 -> A, arr=1 -> B
    auto STG = [&](int arr, int half, int bs, int kk) {
        u16* dst = arr ? (u16*)sB[bs] : (u16*)sA[bs];
        const u16** g = arr ? gB : gA;
#pragma unroll
        for (int is = half * 2; is < half * 2 + 2; ++is)
            gload_lds16(g[is] + kk, dst + dOf[is]);
    };

    // prologue: all 4 halves of kt=0 into buf 0
    STG(0, 0, 0, 0); STG(0, 1, 0, 0); STG(1, 0, 0, 0); STG(1, 1, 0, 0);

    short8 af[4][2], bf[2][2];
    for (int kt = 0; kt < NKT; ++kt) {
        const int cur = kt & 1;
        const int kk = (kt + 1) * 64;
        const int pf = (kt + 1 < NKT);
        const u16* cA = sA[cur];
        const u16* cB = sB[cur];

        // swizzled fragment readers
        auto lda = [&](int row, int g) -> short8 {
            return *(const short8*)&cA[row * 64 + ((g ^ (row & 7)) * 8)];
        };
        auto ldb = [&](int row, int g) -> short8 {
            return *(const short8*)&cB[row * 64 + ((g ^ (row & 7)) * 8)];
        };

#pragma unroll
        for (int ph = 0; ph < 4; ++ph) {
            // phase -> (M-half, N-half); order reuses af across p0/p1, p2/p3
            const int mh = ph >> 1;
            const int nh = (ph == 1 || ph == 2) ? 1 : 0;
            // stage one half-tile of kt+1: p0:Ah0 p1:Ah1 p2:Bh0 p3:Bh1
            if (pf) STG(ph >> 1, ph & 1, cur ^ 1, kk);
            if (ph == 0) {
                if (pf) asm volatile("s_waitcnt vmcnt(2)" ::: "memory");
                else    asm volatile("s_waitcnt vmcnt(0)" ::: "memory");
            }
            __builtin_amdgcn_s_barrier();
            asm volatile("" ::: "memory");
            // ds-load frags for this quadrant (af reused on odd phases)
            if (!(ph & 1)) {
#pragma unroll
                for (int mi = 0; mi < 4; ++mi)
#pragma unroll
                    for (int ks = 0; ks < 2; ++ks)
                        af[mi][ks] = lda(wm * 128 + mh * 64 + mi * 16 + r, ks * 4 + kq);
            }
#pragma unroll
            for (int ni = 0; ni < 2; ++ni)
#pragma unroll
                for (int ks = 0; ks < 2; ++ks)
                    bf[ni][ks] = ldb(wn * 64 + nh * 32 + ni * 16 + r, ks * 4 + kq);
#pragma unroll
            for (int ks = 0; ks < 2; ++ks)
#pragma unroll
                for (int mi = 0; mi < 4; ++mi)
#pragma unroll
                    for (int ni = 0; ni < 2; ++ni)
                        acc[mh * 4 + mi][nh * 2 + ni] =
                            __builtin_amdgcn_mfma_f32_16x16x32_bf16(
                                af[mi][ks], bf[ni][ks],
                                acc[mh * 4 + mi][nh * 2 + ni], 0, 0, 0);
            asm volatile("" ::: "memory");
            __builtin_amdgcn_s_barrier();
            asm volatile("" ::: "memory");
        }
    }

    // epilogue
    const int r4c = kq * 4, cc = lane & 15;
#pragma unroll
    for (int mf = 0; mf < 8; ++mf)
#pragma unroll
        for (int nf = 0; nf < 4; ++nf)
#pragma unroll
            for (int i = 0; i < 4; ++i) {
                const int row = m0 + wm * 128 + mf * 16 + r4c + i;
                const int col = n0 + wn * 64 + nf * 16 + cc;
                C[(size_t)row * N + col] = f2b(acc[mf][nf][i]);
            }
}

// ---- fused per-row ops on P1: rmsnorm(q), rmsnorm(kv), rope_k — one launch --
__global__ __launch_bounds__(256) void normrope_k(const u16* __restrict__ P1,
                                                  const float* __restrict__ qnw,
                                                  const float* __restrict__ kvnw,
                                                  u16* __restrict__ cQb,
                                                  u16* __restrict__ cKVb,
                                                  u16* __restrict__ kRb) {
    const int which = blockIdx.y;
    if (which < 2) {
        const int row = blockIdx.x;
        const int N = which ? 512 : 1024;
        const int off = which ? 1024 : 0;
        const float* w = which ? kvnw : qnw;
        u16* outp = which ? cKVb : cQb;
        const u16* src = P1 + (size_t)row * 1664 + off;
        const int j = threadIdx.x * 4;
        float v[4] = {0.f, 0.f, 0.f, 0.f};
        if (j < N) {
            ushort4 u = *(const ushort4*)(src + j);
            v[0] = b2f(u.x); v[1] = b2f(u.y); v[2] = b2f(u.z); v[3] = b2f(u.w);
        }
        float ss = v[0]*v[0] + v[1]*v[1] + v[2]*v[2] + v[3]*v[3];
#pragma unroll
        for (int offc = 32; offc; offc >>= 1) ss += __shfl_down(ss, offc);
        __shared__ float red[4];
        const int wave = threadIdx.x >> 6, lane = threadIdx.x & 63;
        if (lane == 0) red[wave] = ss;
        __syncthreads();
        const float tot = red[0] + red[1] + red[2] + red[3];
        const float sc = rsqrtf(tot / (float)N + 1e-6f);
        if (j < N) {
            ushort4 o;
            o.x = f2b(v[0] * sc * w[j]);
            o.y = f2b(v[1] * sc * w[j + 1]);
            o.z = f2b(v[2] * sc * w[j + 2]);
            o.w = f2b(v[3] * sc * w[j + 3]);
            *(ushort4*)(outp + (size_t)row * N + j) = o;
        }
    } else {
        // rope_k: 4 rows per block, 64 lanes each
        if (blockIdx.x >= 1024) return;
        const int row = blockIdx.x * 4 + (threadIdx.x >> 6);
        const int j = threadIdx.x & 63;
        const int t = row & (T_ - 1);
        const int i = j & 31;
        const float invf = __expf(-LN_BASE_ * (float)(2 * i) * (1.0f / 64.0f));
        const float ang = (float)t * invf;
        const float c = cosf(ang), s = sinf(ang);
        const u16* src = P1 + (size_t)row * 1664 + 1536;
        const float v = b2f(src[j]);
        const float rot = (j < 32) ? -b2f(src[j + 32]) : b2f(src[j - 32]);
        kRb[(size_t)row * 64 + j] = f2b(v * c + rot * s);
    }
}

// ---- V^T transpose only (RoPE-q fused into attn Q-load) ----------------
__global__ __launch_bounds__(256) void vtrans_k(const u16* __restrict__ P3,
                                                u16* __restrict__ Vt) {
    __shared__ u16 tile[64][72];
    const int tt = blockIdx.x;           // 0..2047
    const int b = tt >> 10;
    const int rem = tt & 1023;
    const int by = rem >> 5, bx = rem & 31;
    const int t0 = by * 64, c0 = bx * 64;
    const int tid = threadIdx.x;
    const int rr2 = tid >> 3;        // 0..31
    const int c8 = tid & 7;          // 16B chunk within 64
#pragma unroll
    for (int p = 0; p < 2; ++p) {
        const int row = p * 32 + rr2;
        *(uint4*)&tile[row][c8 * 8] =
            *(const uint4*)(P3 + (size_t)(b * T_ + t0 + row) * 4096 + 2048 + c0 + c8 * 8);
    }
    __syncthreads();
#pragma unroll
    for (int p = 0; p < 2; ++p) {
        const int c = p * 32 + rr2;
        u16 tmp[8];
#pragma unroll
        for (int j = 0; j < 8; ++j) tmp[j] = tile[c8 * 8 + j][c];
        *(uint4*)(Vt + ((size_t)b * 2048 + c0 + c) * 2048 + t0 + c8 * 8) = *(uint4*)tmp;
    }
}

// ---------------- MFMA flash attention (causal, d=192, dv=128) --------------
// R3 T3/T4 pipelined structure (proven: 94.4us) + R4 RoPE(q) fusion (kept).
// R5: setprio REVERTED (lockstep waves -> T5 starves prefetch issue; m190).
#define ABQ  128
#define ABK  64
#define NW   8
#define KSTR 200   // sK row stride u16 (25 chunks x 8)
#define VSTR 72    // sV row stride u16 (9 chunks x 8)
#define PSTR 72    // sP row stride u16
#define VOFF 12800 // u16 offset of V region inside a KV buffer (25*512)
#define KVSZ 22016 // u16 per KV buffer (43*512)
#define QSTRIDE 3072   // P2 row stride (qC cols 0..2047, qR_raw 2048..3071)
#define KSTRIDE 4096   // P3 row stride (kC cols 0..2047)

__global__ __launch_bounds__(512, 1) void attn_mfma_k(
    const u16* __restrict__ qC,
    const u16* __restrict__ kC, const u16* __restrict__ kR,
    const u16* __restrict__ Vt, u16* __restrict__ outp)
{
    __shared__ __attribute__((aligned(16))) u16 sKV[2][KVSZ];   // 2 x 43 KB
    __shared__ __attribute__((aligned(16))) u16 sP[NW * 16 * PSTR]; // 18 KB

    const int h = blockIdx.x, b = blockIdx.z;                      // x=h: XCD cluster
    const int qb = b ? (15 - (int)blockIdx.y) : (int)blockIdx.y;   // causal balance
    const int q0 = qb * ABQ;
    const int tid = threadIdx.x, wave = tid >> 6, lane = tid & 63;
    const int r = lane & 15, kq = lane >> 4, r4 = kq * 4;
    const int wq = wave * 16;

    // ---- per-wave staging plan: 6 slots each, precomputed bases
    const u16* gsrc[6]; int gstep[6]; int doff[6];
#pragma unroll
    for (int j = 0; j < 6; ++j) {
        const int i = wave + NW * j;              // 0..47
        const int slot = (i < 43) ? i : (i - 43); // pad slots dup K slots 0..4
        if (slot < 25) {                          // K chunk
            const int s = slot * 64 + lane;
            const int rr2 = s / 25;
            int cc = s - rr2 * 25;
            if (cc > 23) cc = 0;                  // pad col: harmless dup
            if (cc < 16) {
                gsrc[j] = kC + (size_t)(b * T_ + rr2) * KSTRIDE + h * 128 + cc * 8;
                gstep[j] = ABK * KSTRIDE;
            } else {
                gsrc[j] = kR + (size_t)(b * T_ + rr2) * 64 + (cc - 16) * 8;
                gstep[j] = ABK * 64;
            }
            doff[j] = slot * 512;
        } else {                                  // V chunk
            const int sl = slot - 25;             // 0..17
            const int s = sl * 64 + lane;
            const int rr2 = s / 9;
            int cc = s - rr2 * 9;
            if (cc > 7) cc = 0;                   // pad col
            gsrc[j] = Vt + ((size_t)(b * H_ + h) * 128 + rr2) * T_ + cc * 8;
            gstep[j] = ABK;
            doff[j] = VOFF + sl * 512;
        }
    }

    // ---- Q fragments in registers; RoPE(q) fused for the rope dims
    short8 qf[6];
    {
        const int t = q0 + wq + r;
        const u16* qcrow = qC + (size_t)(b * T_ + t) * QSTRIDE + h * 128 + kq * 8;
#pragma unroll
        for (int kc = 0; kc < 4; ++kc) qf[kc] = *(const short8*)(qcrow + kc * 32);
        const u16* qrraw = qC + (size_t)(b * T_ + t) * QSTRIDE + 2048 + h * 64 + kq * 8;
        const short8 q0v = *(const short8*)(qrraw);
        const short8 q1v = *(const short8*)(qrraw + 32);
        short8 o0, o1;
#pragma unroll
        for (int j = 0; j < 8; ++j) {
            const int i = kq * 8 + j;             // dim mod 32 (same for both halves)
            const float invf = __expf(-LN_BASE_ * (float)(2 * i) * (1.0f / 64.0f));
            const float ang = (float)t * invf;
            const float cs = cosf(ang), sn = sinf(ang);
            const float a = b2f((u16)q0v[j]), bb = b2f((u16)q1v[j]);
            o0[j] = (short)f2b(a * cs - bb * sn);
            o1[j] = (short)f2b(bb * cs + a * sn);
        }
        qf[4] = o0; qf[5] = o1;
    }

    f32x4 Oa[8];
#pragma unroll
    for (int nt = 0; nt < 8; ++nt) Oa[nt] = (f32x4){0.f, 0.f, 0.f, 0.f};
    float Lrow[4] = {0.f, 0.f, 0.f, 0.f};

    u16* myP = sP + wave * 16 * PSTR;

    auto STAGE = [&](int kt2, int bs) {
        u16* dst = &sKV[bs][0];
#pragma unroll
        for (int j = 0; j < 6; ++j)
            gload_lds16(gsrc[j] + (size_t)kt2 * (size_t)gstep[j], dst + doff[j]);
    };

    const int nkt = 2 * qb + 2;
    STAGE(0, 0);
    for (int kt = 0; kt < nkt; ++kt) {
        const int cur = kt & 1;
        if (kt + 1 < nkt) STAGE(kt + 1, cur ^ 1);
        if (kt == 0 || kt + 1 >= nkt) {
            asm volatile("s_waitcnt vmcnt(0)" ::: "memory");
        } else {
            asm volatile("s_waitcnt vmcnt(6)" ::: "memory");
        }
        __builtin_amdgcn_s_barrier();
        asm volatile("" ::: "memory");

        const u16* cK = &sKV[cur][0];
        const u16* cV = &sKV[cur][VOFF];
        const int k0 = kt * ABK;

        // ---- S = Q K^T  (24 MFMA/wave)
        f32x4 Sa[4];
#pragma unroll
        for (int nt = 0; nt < 4; ++nt) Sa[nt] = (f32x4){0.f, 0.f, 0.f, 0.f};
#pragma unroll
        for (int kc = 0; kc < 6; ++kc) {
            short8 kf[4];
#pragma unroll
            for (int nt = 0; nt < 4; ++nt)
                kf[nt] = *(const short8*)&cK[(nt * 16 + r) * KSTR + (kc * 4 + kq) * 8];
#pragma unroll
            for (int nt = 0; nt < 4; ++nt)
                Sa[nt] = __builtin_amdgcn_mfma_f32_16x16x32_bf16(
                    qf[kc], kf[nt], Sa[nt], 0, 0, 0);
        }

        // ---- no-max softmax: p = exp2(S*SC2); wave-uniform mask split
        if (kt < nkt - 2) {
#pragma unroll
            for (int i = 0; i < 4; ++i) {
                float sm = 0.f;
#pragma unroll
                for (int nt = 0; nt < 4; ++nt) {
                    const float p = exp2f(Sa[nt][i] * SC2_);
                    sm += p;
                    myP[(r4 + i) * PSTR + nt * 16 + r] = f2b_fast(p);
                }
                Lrow[i] += sm;
            }
        } else {
#pragma unroll
            for (int i = 0; i < 4; ++i) {
                const int grow = q0 + wq + r4 + i;
                float sm = 0.f;
#pragma unroll
                for (int nt = 0; nt < 4; ++nt) {
                    float p = exp2f(Sa[nt][i] * SC2_);
                    p = (k0 + nt * 16 + r > grow) ? 0.f : p;
                    sm += p;
                    myP[(r4 + i) * PSTR + nt * 16 + r] = f2b_fast(p);
                }
                Lrow[i] += sm;
            }
        }

        // ---- O += P V  (P wave-local; same-wave DS order via lgkmcnt)
#pragma unroll
        for (int kc2 = 0; kc2 < 2; ++kc2) {
            const short8 pf = *(const short8*)&myP[r * PSTR + (kc2 * 4 + kq) * 8];
#pragma unroll
            for (int nt = 0; nt < 8; ++nt) {
                const short8 vf = *(const short8*)&cV[(nt * 16 + r) * VSTR + (kc2 * 4 + kq) * 8];
                Oa[nt] = __builtin_amdgcn_mfma_f32_16x16x32_bf16(
                    pf, vf, Oa[nt], 0, 0, 0);
            }
        }

        // release: all waves done reading buf[cur] before kt+1 stages into it
        asm volatile("" ::: "memory");
        __builtin_amdgcn_s_barrier();
        asm volatile("" ::: "memory");
    }

    // ---- epilogue: reduce L across the 16 lanes of each quad-group, O /= L
#pragma unroll
    for (int i = 0; i < 4; ++i) {
        float L = Lrow[i];
        L += __shfl_xor(L, 1);
        L += __shfl_xor(L, 2);
        L += __shfl_xor(L, 4);
        L += __shfl_xor(L, 8);
        const float inv = 1.0f / L;
        const int t = q0 + wq + r4 + i;
        u16* orow = outp + (size_t)(b * T_ + t) * 2048 + h * 128;
#pragma unroll
        for (int nt = 0; nt < 8; ++nt)
            orow[nt * 16 + r] = f2b(Oa[nt][i] * inv);
    }
}

// ---------------- host side -------------------------------------------------
// Workspace plan: 139.46 MB (proven safe). U1 time-shared: P1 then attn_out.
// Vt reuses xb. 8 dispatches: prep -> proj1 -> normrope -> proj2a(128^2) ->
// proj2b(256^2 8-wave, PROMOTED) -> vtrans -> attn -> WO
extern "C" void kernel_launch(void* const* d_in, const int* in_sizes, int n_in,
                              void* d_out, int out_size, void* d_ws, size_t ws_size,
                              hipStream_t stream) {
    (void)in_sizes; (void)n_in; (void)out_size; (void)ws_size;
    const float* x     = (const float*)d_in[0];
    const float* W_DQ  = (const float*)d_in[1];
    const float* W_UQ  = (const float*)d_in[2];
    const float* W_QR  = (const float*)d_in[3];
    const float* W_DKV = (const float*)d_in[4];
    const float* W_UK  = (const float*)d_in[5];
    const float* W_UV  = (const float*)d_in[6];
    const float* W_KR  = (const float*)d_in[7];
    const float* W_O   = (const float*)d_in[8];
    const float* qnw   = (const float*)d_in[9];
    const float* kvnw  = (const float*)d_in[10];
    float* out = (float*)d_out;   // fp32 output per reference dtype

    char* base = (char*)d_ws;
    size_t o = 0;
    auto alloc = [&](size_t bytes) {
        char* r = base + o;
        o += (bytes + 255) & ~(size_t)255;
        return r;
    };
    u16* WT1  = (u16*)alloc((size_t)1664 * 2048 * 2);
    u16* WT2  = (u16*)alloc((size_t)3072 * 1024 * 2);
    u16* WT3  = (u16*)alloc((size_t)4096 * 512 * 2);
    u16* WT_O = (u16*)alloc((size_t)2048 * 2048 * 2);
    u16* xb   = (u16*)alloc((size_t)M_ * 2048 * 2);    // x bf16; later Vt
    u16* U1   = (u16*)alloc((size_t)M_ * 2048 * 2);    // P1 then attn_out
    u16* P2   = (u16*)alloc((size_t)M_ * 3072 * 2);    // [qC | qR_raw]
    u16* P3   = (u16*)alloc((size_t)M_ * 4096 * 2);    // [kC | vC]
    u16* cQb  = (u16*)alloc((size_t)M_ * 1024 * 2);
    u16* cKVb = (u16*)alloc((size_t)M_ * 512 * 2);
    u16* qRb  = (u16*)alloc((size_t)M_ * 1024 * 2);    // (unused; layout kept)
    u16* kRb  = (u16*)alloc((size_t)M_ * 64 * 2);
    (void)qRb;
    u16* P1       = U1;
    u16* attn_out = U1;
    u16* Vt       = xb;

    // ---- dispatch 1: all 8 weight transposes + x cast
    TPack tp;
    const float* srcs[8] = {W_DQ, W_DKV, W_KR, W_UQ, W_QR, W_UK, W_UV, W_O};
    u16* dsts[8] = {WT1, WT1 + (size_t)1024*2048, WT1 + (size_t)1536*2048,
                    WT2, WT2 + (size_t)2048*1024,
                    WT3, WT3 + (size_t)2048*512, WT_O};
    const int Ks[8]   = {2048, 2048, 2048, 1024, 1024, 512, 512, 2048};
    const int Ns[8]   = {1024,  512,   64, 2048, 1024, 2048, 2048, 2048};
    const int ntxs[8] = {  32,   16,    4,   64,   32,   64,   64,   64};
    int cum = 0;
    for (int i = 0; i < 8; ++i) {
        tp.src[i] = srcs[i]; tp.dst[i] = dsts[i];
        tp.K[i] = Ks[i]; tp.N[i] = Ns[i]; tp.ntx[i] = ntxs[i];
        tp.start[i] = cum;
        cum += ntxs[i] * (Ks[i] / 32);
    }
    tp.start[8] = cum;   // 12544 transpose tiles
    const int ncast = (M_ * D_) / 1024;   // 8192 cast blocks
    prep_k<<<cum + ncast, 256, 0, stream>>>(tp, x, xb, cum);

    // ---- dispatch 2: proj1: x @ [W_DQ | W_DKV | W_KR] -> P1 (M x 1664)
    gemm_tn<1><<<dim3(1664/128, M_/128), 256, 0, stream>>>(xb, WT1, (void*)P1, 1664, 2048);

    // ---- dispatch 3: fused rmsnorm(q) + rmsnorm(kv) + rope_k
    normrope_k<<<dim3(M_, 3), 256, 0, stream>>>(P1, qnw, kvnw, cQb, cKVb, kRb);

    // ---- dispatch 4: proj2a: cQ @ [W_UQ|W_QR] -> P2 (128^2 structure)
    gemm_tn<1><<<dim3(3072/128, M_/128), 256, 0, stream>>>(cQb, WT2, (void*)P2, 3072, 1024);

    // ---- dispatch 5: proj2b: cKV @ [W_UK|W_UV] -> P3 (256^2 8-wave, REAL)
    gemm256_k<<<dim3(4096/256, M_/256), 512, 0, stream>>>(cKVb, WT3, P3, 4096, 512);

    // ---- dispatch 6: V^T transpose (RoPE-q fused into attn)
    vtrans_k<<<2048, 256, 0, stream>>>(P3, Vt);

    // ---- dispatch 7: attention — 512 thr/block; grid x=h (XCD), y=qb, z=b
    attn_mfma_k<<<dim3(H_, T_/ABQ, B_), 512, 0, stream>>>(P2, P3, kRb, Vt, attn_out);

    // ---- dispatch 8: output projection -> d_out (fp32)
    gemm_tn<0><<<dim3(2048/128, M_/128), 256, 0, stream>>>(attn_out, WT_O, (void*)out, 2048, 2048);
}

// Round 6
// 396.699 us; speedup vs baseline: 1.1109x; 1.0491x over previous
//
#include <hip/hip_runtime.h>
#include <cstdint>
#include <cstddef>

// ---------------- problem constants ----------------
#define B_   2
#define T_   2048
#define D_   2048
#define H_   16
#define DH_  128
#define DQ_  1024
#define DKV_ 512
#define DR_  64
#define M_   4096            // B_*T_
#define SCALE_ 0.07216878364870323f   // 1/sqrt(DH_+DR_)
#define SC2_   0.10412808709930322f   // SCALE_ * log2(e)
#define LN_BASE_ 13.122363377404328f  // ln(500000)

typedef unsigned short u16;
typedef __attribute__((ext_vector_type(8))) short short8;   // 8 bf16 (4 VGPRs)
typedef __attribute__((ext_vector_type(4))) float f32x4;    // 4 fp32 acc

__device__ __forceinline__ float b2f(u16 u) { return __uint_as_float(((uint32_t)u) << 16); }
__device__ __forceinline__ u16 f2b(float f) {            // RNE
    uint32_t x = __float_as_uint(f);
    return (u16)((x + 0x7fffu + ((x >> 16) & 1u)) >> 16);
}
__device__ __forceinline__ u16 f2b_fast(float f) {       // round-up-ties, 2 ops
    return (u16)((__float_as_uint(f) + 0x8000u) >> 16);
}

__device__ __forceinline__ void gload_lds16(const u16* src, u16* dst) {
    __builtin_amdgcn_global_load_lds(
        (const __attribute__((address_space(1))) uint32_t*)(uintptr_t)src,
        (__attribute__((address_space(3))) uint32_t*)(uintptr_t)dst, 16, 0, 0);
}

// ---- fused prep: 8 weight transposes (+cast) AND x fp32->bf16, one launch ---
struct TPack {
    const float* src[8];
    u16*         dst[8];
    int K[8];      // src rows
    int N[8];      // src cols (real)
    int ntx[8];    // tiles along out-row dim (covers padded N)
    int start[9];  // cumulative tile offsets
};

__global__ __launch_bounds__(256) void prep_k(TPack p, const float* __restrict__ x,
                                              u16* __restrict__ xb, int ntr) {
    const int bid = blockIdx.x;
    if (bid < ntr) {
        __shared__ float tile[32][33];
        int w = 0;
#pragma unroll
        for (int i = 1; i < 8; ++i) if (bid >= p.start[i]) w = i;
        const int lt = bid - p.start[w];
        const int bx = lt % p.ntx[w], by = lt / p.ntx[w];
        const float* in = p.src[w];
        u16* out = p.dst[w];
        const int K = p.K[w], N = p.N[w];
        const int k0 = by * 32, n0 = bx * 32;
        const int tx = threadIdx.x & 31, ty = threadIdx.x >> 5;  // 32x8
#pragma unroll
        for (int i = 0; i < 4; ++i) {
            int k = k0 + ty + i * 8;
            int n = n0 + tx;
            tile[ty + i * 8][tx] = (n < N) ? in[(size_t)k * N + n] : 0.f;
        }
        __syncthreads();
#pragma unroll
        for (int i = 0; i < 4; ++i) {
            int n = n0 + ty + i * 8;     // out row
            out[(size_t)n * K + k0 + tx] = f2b(tile[tx][ty + i * 8]);
        }
    } else {
        const int i = ((bid - ntr) * 256 + threadIdx.x) * 4;
        const float4 v = *(const float4*)(x + i);
        ushort4 o;
        o.x = f2b(v.x); o.y = f2b(v.y); o.z = f2b(v.z); o.w = f2b(v.w);
        *(ushort4*)(xb + i) = o;
    }
}

// ---------------- bf16 GEMM:  C(MxN) = A(MxK) @ B(KxN), Bt given as NxK ------
template <int OUT_BF16>
__global__ __launch_bounds__(256) void gemm_tn(const u16* __restrict__ A,
                                               const u16* __restrict__ Bt,
                                               void* __restrict__ Cv,
                                               int N, int K) {
    __shared__ __attribute__((aligned(16))) u16 lA[128 * 32];
    __shared__ __attribute__((aligned(16))) u16 lB[128 * 32];
    const int m0 = blockIdx.y * 128, n0 = blockIdx.x * 128;
    const int tid = threadIdx.x, wave = tid >> 6, lane = tid & 63;
    const int wm = (wave >> 1) * 64, wn = (wave & 1) * 64;
    const int r = lane & 15, kq = lane >> 4;

    f32x4 acc[4][4];
#pragma unroll
    for (int i = 0; i < 4; ++i)
#pragma unroll
        for (int j = 0; j < 4; ++j) acc[i][j] = (f32x4){0.f, 0.f, 0.f, 0.f};

    for (int kk = 0; kk < K; kk += 32) {
#pragma unroll
        for (int p = 0; p < 2; ++p) {
            const int c = p * 256 + wave * 64 + lane;          // 16B chunk id
            const u16* ga = A  + (size_t)(m0 + (c >> 2)) * K + kk + (c & 3) * 8;
            const u16* gb = Bt + (size_t)(n0 + (c >> 2)) * K + kk + (c & 3) * 8;
            u16* la = lA + (size_t)(p * 256 + wave * 64) * 8;  // wave-uniform base
            u16* lb = lB + (size_t)(p * 256 + wave * 64) * 8;
            gload_lds16(ga, la);
            gload_lds16(gb, lb);
        }
        __syncthreads();
        short8 av[4], bv[4];
#pragma unroll
        for (int mi = 0; mi < 4; ++mi)
            av[mi] = *(const short8*)&lA[(wm + mi * 16 + r) * 32 + kq * 8];
#pragma unroll
        for (int ni = 0; ni < 4; ++ni)
            bv[ni] = *(const short8*)&lB[(wn + ni * 16 + r) * 32 + kq * 8];
#pragma unroll
        for (int mi = 0; mi < 4; ++mi)
#pragma unroll
            for (int ni = 0; ni < 4; ++ni)
                acc[mi][ni] = __builtin_amdgcn_mfma_f32_16x16x32_bf16(
                    av[mi], bv[ni], acc[mi][ni], 0, 0, 0);
        __syncthreads();
    }
    const int r4 = (lane >> 4) * 4, cc = lane & 15;
#pragma unroll
    for (int mi = 0; mi < 4; ++mi)
#pragma unroll
        for (int ni = 0; ni < 4; ++ni)
#pragma unroll
            for (int i = 0; i < 4; ++i) {
                const int row = m0 + wm + mi * 16 + r4 + i;
                const int col = n0 + wn + ni * 16 + cc;
                const float v = acc[mi][ni][i];
                if (OUT_BF16) ((u16*)Cv)[(size_t)row * N + col] = f2b(v);
                else          ((float*)Cv)[(size_t)row * N + col] = v;
            }
}

// ---- 256x256 8-wave pipelined GEMM (T2 swizzle + T3/T4 counted vmcnt) ------
// proj2b (cKV @ [W_UK|W_UV] -> P3). Verified R5; ~break-even with 128^2 at
// K=512 (pipeline too shallow to win at 8 K-tiles). Kept: costs nothing.
#define S_BM 256
#define S_BN 256
#define S_BK 64

__global__ __launch_bounds__(512, 1) void gemm256_k(const u16* __restrict__ A,
                                                    const u16* __restrict__ Bt,
                                                    u16* __restrict__ C,
                                                    int N, int K) {
    __shared__ __attribute__((aligned(16))) u16 sA[2][S_BM * S_BK]; // 2 x 32 KB
    __shared__ __attribute__((aligned(16))) u16 sB[2][S_BN * S_BK]; // 2 x 32 KB
    const int m0 = blockIdx.y * S_BM, n0 = blockIdx.x * S_BN;
    const int tid = threadIdx.x, lane = tid & 63;
    const int wave = tid >> 6;
    const int wm = wave >> 2, wn = wave & 3;          // 2 x 4 wave grid
    const int r = lane & 15, kq = lane >> 4;

    const u16* gA[4]; const u16* gB[4]; int dOf[4];
#pragma unroll
    for (int is = 0; is < 4; ++is) {
        const int c = is * 512 + tid;
        const int row = c >> 3, c16 = c & 7;
        gA[is] = A  + (size_t)(m0 + row) * K + ((c16 ^ (row & 7)) * 8);
        gB[is] = Bt + (size_t)(n0 + row) * K + ((c16 ^ (row & 7)) * 8);
        dOf[is] = c * 8;
    }

    f32x4 acc[8][4];
#pragma unroll
    for (int i = 0; i < 8; ++i)
#pragma unroll
        for (int j = 0; j < 4; ++j) acc[i][j] = (f32x4){0.f, 0.f, 0.f, 0.f};

    const int NKT = K >> 6;

    auto STG = [&](int arr, int half, int bs, int kk) {
        u16* dst = arr ? (u16*)sB[bs] : (u16*)sA[bs];
        const u16** g = arr ? gB : gA;
#pragma unroll
        for (int is = half * 2; is < half * 2 + 2; ++is)
            gload_lds16(g[is] + kk, dst + dOf[is]);
    };

    STG(0, 0, 0, 0); STG(0, 1, 0, 0); STG(1, 0, 0, 0); STG(1, 1, 0, 0);

    short8 af[4][2], bf[2][2];
    for (int kt = 0; kt < NKT; ++kt) {
        const int cur = kt & 1;
        const int kk = (kt + 1) * 64;
        const int pf = (kt + 1 < NKT);
        const u16* cA = sA[cur];
        const u16* cB = sB[cur];

        auto lda = [&](int row, int g) -> short8 {
            return *(const short8*)&cA[row * 64 + ((g ^ (row & 7)) * 8)];
        };
        auto ldb = [&](int row, int g) -> short8 {
            return *(const short8*)&cB[row * 64 + ((g ^ (row & 7)) * 8)];
        };

#pragma unroll
        for (int ph = 0; ph < 4; ++ph) {
            const int mh = ph >> 1;
            const int nh = (ph == 1 || ph == 2) ? 1 : 0;
            if (pf) STG(ph >> 1, ph & 1, cur ^ 1, kk);
            if (ph == 0) {
                if (pf) asm volatile("s_waitcnt vmcnt(2)" ::: "memory");
                else    asm volatile("s_waitcnt vmcnt(0)" ::: "memory");
            }
            __builtin_amdgcn_s_barrier();
            asm volatile("" ::: "memory");
            if (!(ph & 1)) {
#pragma unroll
                for (int mi = 0; mi < 4; ++mi)
#pragma unroll
                    for (int ks = 0; ks < 2; ++ks)
                        af[mi][ks] = lda(wm * 128 + mh * 64 + mi * 16 + r, ks * 4 + kq);
            }
#pragma unroll
            for (int ni = 0; ni < 2; ++ni)
#pragma unroll
                for (int ks = 0; ks < 2; ++ks)
                    bf[ni][ks] = ldb(wn * 64 + nh * 32 + ni * 16 + r, ks * 4 + kq);
#pragma unroll
            for (int ks = 0; ks < 2; ++ks)
#pragma unroll
                for (int mi = 0; mi < 4; ++mi)
#pragma unroll
                    for (int ni = 0; ni < 2; ++ni)
                        acc[mh * 4 + mi][nh * 2 + ni] =
                            __builtin_amdgcn_mfma_f32_16x16x32_bf16(
                                af[mi][ks], bf[ni][ks],
                                acc[mh * 4 + mi][nh * 2 + ni], 0, 0, 0);
            asm volatile("" ::: "memory");
            __builtin_amdgcn_s_barrier();
            asm volatile("" ::: "memory");
        }
    }

    const int r4c = kq * 4, cc = lane & 15;
#pragma unroll
    for (int mf = 0; mf < 8; ++mf)
#pragma unroll
        for (int nf = 0; nf < 4; ++nf)
#pragma unroll
            for (int i = 0; i < 4; ++i) {
                const int row = m0 + wm * 128 + mf * 16 + r4c + i;
                const int col = n0 + wn * 64 + nf * 16 + cc;
                C[(size_t)row * N + col] = f2b(acc[mf][nf][i]);
            }
}

// ---- fused per-row ops on P1: rmsnorm(q), rmsnorm(kv), rope_k — one launch --
__global__ __launch_bounds__(256) void normrope_k(const u16* __restrict__ P1,
                                                  const float* __restrict__ qnw,
                                                  const float* __restrict__ kvnw,
                                                  u16* __restrict__ cQb,
                                                  u16* __restrict__ cKVb,
                                                  u16* __restrict__ kRb) {
    const int which = blockIdx.y;
    if (which < 2) {
        const int row = blockIdx.x;
        const int N = which ? 512 : 1024;
        const int off = which ? 1024 : 0;
        const float* w = which ? kvnw : qnw;
        u16* outp = which ? cKVb : cQb;
        const u16* src = P1 + (size_t)row * 1664 + off;
        const int j = threadIdx.x * 4;
        float v[4] = {0.f, 0.f, 0.f, 0.f};
        if (j < N) {
            ushort4 u = *(const ushort4*)(src + j);
            v[0] = b2f(u.x); v[1] = b2f(u.y); v[2] = b2f(u.z); v[3] = b2f(u.w);
        }
        float ss = v[0]*v[0] + v[1]*v[1] + v[2]*v[2] + v[3]*v[3];
#pragma unroll
        for (int offc = 32; offc; offc >>= 1) ss += __shfl_down(ss, offc);
        __shared__ float red[4];
        const int wave = threadIdx.x >> 6, lane = threadIdx.x & 63;
        if (lane == 0) red[wave] = ss;
        __syncthreads();
        const float tot = red[0] + red[1] + red[2] + red[3];
        const float sc = rsqrtf(tot / (float)N + 1e-6f);
        if (j < N) {
            ushort4 o;
            o.x = f2b(v[0] * sc * w[j]);
            o.y = f2b(v[1] * sc * w[j + 1]);
            o.z = f2b(v[2] * sc * w[j + 2]);
            o.w = f2b(v[3] * sc * w[j + 3]);
            *(ushort4*)(outp + (size_t)row * N + j) = o;
        }
    } else {
        // rope_k: 4 rows per block, 64 lanes each
        if (blockIdx.x >= 1024) return;
        const int row = blockIdx.x * 4 + (threadIdx.x >> 6);
        const int j = threadIdx.x & 63;
        const int t = row & (T_ - 1);
        const int i = j & 31;
        const float invf = __expf(-LN_BASE_ * (float)(2 * i) * (1.0f / 64.0f));
        const float ang = (float)t * invf;
        const float c = cosf(ang), s = sinf(ang);
        const u16* src = P1 + (size_t)row * 1664 + 1536;
        const float v = b2f(src[j]);
        const float rot = (j < 32) ? -b2f(src[j + 32]) : b2f(src[j - 32]);
        kRb[(size_t)row * 64 + j] = f2b(v * c + rot * s);
    }
}

// ---- V^T transpose only (RoPE-q fused into attn Q-load) ----------------
__global__ __launch_bounds__(256) void vtrans_k(const u16* __restrict__ P3,
                                                u16* __restrict__ Vt) {
    __shared__ u16 tile[64][72];
    const int tt = blockIdx.x;           // 0..2047
    const int b = tt >> 10;
    const int rem = tt & 1023;
    const int by = rem >> 5, bx = rem & 31;
    const int t0 = by * 64, c0 = bx * 64;
    const int tid = threadIdx.x;
    const int rr2 = tid >> 3;        // 0..31
    const int c8 = tid & 7;          // 16B chunk within 64
#pragma unroll
    for (int p = 0; p < 2; ++p) {
        const int row = p * 32 + rr2;
        *(uint4*)&tile[row][c8 * 8] =
            *(const uint4*)(P3 + (size_t)(b * T_ + t0 + row) * 4096 + 2048 + c0 + c8 * 8);
    }
    __syncthreads();
#pragma unroll
    for (int p = 0; p < 2; ++p) {
        const int c = p * 32 + rr2;
        u16 tmp[8];
#pragma unroll
        for (int j = 0; j < 8; ++j) tmp[j] = tile[c8 * 8 + j][c];
        *(uint4*)(Vt + ((size_t)b * 2048 + c0 + c) * 2048 + t0 + c8 * 8) = *(uint4*)tmp;
    }
}

// ---------------- MFMA flash attention (causal, d=192, dv=128) --------------
// R6: 3-buffer, depth-2 prefetch, ONE barrier per K-tile.
//  Iteration: [vmcnt(N); s_barrier; compute(kt) on buf[kt%3]; STAGE(kt+2)].
//  Acquire: kt's 6 loads (issued 2 iters ago) are the 6 oldest; vmcnt(6)
//  completes them; barrier broadcasts across waves. Buffer protect:
//  STAGE(kt+2) writes buf[(kt+2)%3], last read by compute(kt-1), which every
//  wave finished BEFORE barrier(kt) -> no second barrier needed.
//  vmcnt ladder: kt==0 -> 0 (drains Q loads); kt==nkt-1 -> 0 (no deeper
//  prefetch outstanding); else 6.
#define ABQ  128
#define ABK  64
#define NW   8
#define KSTR 200   // sK row stride u16 (25 chunks x 8)
#define VSTR 72    // sV row stride u16 (9 chunks x 8)
#define PSTR 72    // sP row stride u16
#define VOFF 12800 // u16 offset of V region inside a KV buffer (25*512)
#define KVSZ 22016 // u16 per KV buffer (43*512)
#define QSTRIDE 3072   // P2 row stride (qC cols 0..2047, qR_raw 2048..3071)
#define KSTRIDE 4096   // P3 row stride (kC cols 0..2047)

__global__ __launch_bounds__(512, 1) void attn_mfma_k(
    const u16* __restrict__ qC,
    const u16* __restrict__ kC, const u16* __restrict__ kR,
    const u16* __restrict__ Vt, u16* __restrict__ outp)
{
    __shared__ __attribute__((aligned(16))) u16 sKV[3][KVSZ];   // 3 x 43 KB = 129 KB
    __shared__ __attribute__((aligned(16))) u16 sP[NW * 16 * PSTR]; // 18 KB

    const int h = blockIdx.x, b = blockIdx.z;                      // x=h: XCD cluster
    const int qb = b ? (15 - (int)blockIdx.y) : (int)blockIdx.y;   // causal balance
    const int q0 = qb * ABQ;
    const int tid = threadIdx.x, wave = tid >> 6, lane = tid & 63;
    const int r = lane & 15, kq = lane >> 4, r4 = kq * 4;
    const int wq = wave * 16;

    // ---- per-wave staging plan: 6 slots each, precomputed bases
    const u16* gsrc[6]; int gstep[6]; int doff[6];
#pragma unroll
    for (int j = 0; j < 6; ++j) {
        const int i = wave + NW * j;              // 0..47
        const int slot = (i < 43) ? i : (i - 43); // pad slots dup K slots 0..4
        if (slot < 25) {                          // K chunk
            const int s = slot * 64 + lane;
            const int rr2 = s / 25;
            int cc = s - rr2 * 25;
            if (cc > 23) cc = 0;                  // pad col: harmless dup
            if (cc < 16) {
                gsrc[j] = kC + (size_t)(b * T_ + rr2) * KSTRIDE + h * 128 + cc * 8;
                gstep[j] = ABK * KSTRIDE;
            } else {
                gsrc[j] = kR + (size_t)(b * T_ + rr2) * 64 + (cc - 16) * 8;
                gstep[j] = ABK * 64;
            }
            doff[j] = slot * 512;
        } else {                                  // V chunk
            const int sl = slot - 25;             // 0..17
            const int s = sl * 64 + lane;
            const int rr2 = s / 9;
            int cc = s - rr2 * 9;
            if (cc > 7) cc = 0;                   // pad col
            gsrc[j] = Vt + ((size_t)(b * H_ + h) * 128 + rr2) * T_ + cc * 8;
            gstep[j] = ABK;
            doff[j] = VOFF + sl * 512;
        }
    }

    // ---- Q fragments in registers; RoPE(q) fused for the rope dims
    short8 qf[6];
    {
        const int t = q0 + wq + r;
        const u16* qcrow = qC + (size_t)(b * T_ + t) * QSTRIDE + h * 128 + kq * 8;
#pragma unroll
        for (int kc = 0; kc < 4; ++kc) qf[kc] = *(const short8*)(qcrow + kc * 32);
        const u16* qrraw = qC + (size_t)(b * T_ + t) * QSTRIDE + 2048 + h * 64 + kq * 8;
        const short8 q0v = *(const short8*)(qrraw);
        const short8 q1v = *(const short8*)(qrraw + 32);
        short8 o0, o1;
#pragma unroll
        for (int j = 0; j < 8; ++j) {
            const int i = kq * 8 + j;             // dim mod 32 (same for both halves)
            const float invf = __expf(-LN_BASE_ * (float)(2 * i) * (1.0f / 64.0f));
            const float ang = (float)t * invf;
            const float cs = cosf(ang), sn = sinf(ang);
            const float a = b2f((u16)q0v[j]), bb = b2f((u16)q1v[j]);
            o0[j] = (short)f2b(a * cs - bb * sn);
            o1[j] = (short)f2b(bb * cs + a * sn);
        }
        qf[4] = o0; qf[5] = o1;
    }

    f32x4 Oa[8];
#pragma unroll
    for (int nt = 0; nt < 8; ++nt) Oa[nt] = (f32x4){0.f, 0.f, 0.f, 0.f};
    float Lrow[4] = {0.f, 0.f, 0.f, 0.f};

    u16* myP = sP + wave * 16 * PSTR;

    auto STAGE = [&](int kt2, int bs) {
        u16* dst = &sKV[bs][0];
#pragma unroll
        for (int j = 0; j < 6; ++j)
            gload_lds16(gsrc[j] + (size_t)kt2 * (size_t)gstep[j], dst + doff[j]);
    };

    const int nkt = 2 * qb + 2;   // >= 2 always
    STAGE(0, 0);
    STAGE(1, 1);
    for (int kt = 0; kt < nkt; ++kt) {
        const int cur = kt % 3;
        // acquire: tile kt's 6 loads are the oldest outstanding
        if (kt == 0 || kt >= nkt - 1) {
            asm volatile("s_waitcnt vmcnt(0)" ::: "memory");
        } else {
            asm volatile("s_waitcnt vmcnt(6)" ::: "memory");
        }
        __builtin_amdgcn_s_barrier();
        asm volatile("" ::: "memory");

        const u16* cK = &sKV[cur][0];
        const u16* cV = &sKV[cur][VOFF];
        const int k0 = kt * ABK;

        // ---- S = Q K^T  (24 MFMA/wave)
        f32x4 Sa[4];
#pragma unroll
        for (int nt = 0; nt < 4; ++nt) Sa[nt] = (f32x4){0.f, 0.f, 0.f, 0.f};
#pragma unroll
        for (int kc = 0; kc < 6; ++kc) {
            short8 kf[4];
#pragma unroll
            for (int nt = 0; nt < 4; ++nt)
                kf[nt] = *(const short8*)&cK[(nt * 16 + r) * KSTR + (kc * 4 + kq) * 8];
#pragma unroll
            for (int nt = 0; nt < 4; ++nt)
                Sa[nt] = __builtin_amdgcn_mfma_f32_16x16x32_bf16(
                    qf[kc], kf[nt], Sa[nt], 0, 0, 0);
        }

        // ---- no-max softmax: p = exp2(S*SC2); wave-uniform mask split
        if (kt < nkt - 2) {
#pragma unroll
            for (int i = 0; i < 4; ++i) {
                float sm = 0.f;
#pragma unroll
                for (int nt = 0; nt < 4; ++nt) {
                    const float p = exp2f(Sa[nt][i] * SC2_);
                    sm += p;
                    myP[(r4 + i) * PSTR + nt * 16 + r] = f2b_fast(p);
                }
                Lrow[i] += sm;
            }
        } else {
#pragma unroll
            for (int i = 0; i < 4; ++i) {
                const int grow = q0 + wq + r4 + i;
                float sm = 0.f;
#pragma unroll
                for (int nt = 0; nt < 4; ++nt) {
                    float p = exp2f(Sa[nt][i] * SC2_);
                    p = (k0 + nt * 16 + r > grow) ? 0.f : p;
                    sm += p;
                    myP[(r4 + i) * PSTR + nt * 16 + r] = f2b_fast(p);
                }
                Lrow[i] += sm;
            }
        }

        // ---- O += P V  (P wave-local; same-wave DS order via lgkmcnt)
#pragma unroll
        for (int kc2 = 0; kc2 < 2; ++kc2) {
            const short8 pf = *(const short8*)&myP[r * PSTR + (kc2 * 4 + kq) * 8];
#pragma unroll
            for (int nt = 0; nt < 8; ++nt) {
                const short8 vf = *(const short8*)&cV[(nt * 16 + r) * VSTR + (kc2 * 4 + kq) * 8];
                Oa[nt] = __builtin_amdgcn_mfma_f32_16x16x32_bf16(
                    pf, vf, Oa[nt], 0, 0, 0);
            }
        }

        // ---- prefetch depth 2: stage tile kt+2 into buf[(kt+2)%3].
        // Safe: its last reader (compute(kt-1)) finished before barrier(kt).
        if (kt + 2 < nkt) STAGE(kt + 2, (kt + 2) % 3);
    }

    // ---- epilogue: reduce L across the 16 lanes of each quad-group, O /= L
#pragma unroll
    for (int i = 0; i < 4; ++i) {
        float L = Lrow[i];
        L += __shfl_xor(L, 1);
        L += __shfl_xor(L, 2);
        L += __shfl_xor(L, 4);
        L += __shfl_xor(L, 8);
        const float inv = 1.0f / L;
        const int t = q0 + wq + r4 + i;
        u16* orow = outp + (size_t)(b * T_ + t) * 2048 + h * 128;
#pragma unroll
        for (int nt = 0; nt < 8; ++nt)
            orow[nt * 16 + r] = f2b(Oa[nt][i] * inv);
    }
}

// ---------------- host side -------------------------------------------------
// Workspace plan: 139.46 MB (proven safe). U1 time-shared: P1 then attn_out.
// Vt reuses xb. 8 dispatches: prep -> proj1 -> normrope -> proj2a(128^2) ->
// proj2b(256^2 8-wave) -> vtrans -> attn(3-buf) -> WO
extern "C" void kernel_launch(void* const* d_in, const int* in_sizes, int n_in,
                              void* d_out, int out_size, void* d_ws, size_t ws_size,
                              hipStream_t stream) {
    (void)in_sizes; (void)n_in; (void)out_size; (void)ws_size;
    const float* x     = (const float*)d_in[0];
    const float* W_DQ  = (const float*)d_in[1];
    const float* W_UQ  = (const float*)d_in[2];
    const float* W_QR  = (const float*)d_in[3];
    const float* W_DKV = (const float*)d_in[4];
    const float* W_UK  = (const float*)d_in[5];
    const float* W_UV  = (const float*)d_in[6];
    const float* W_KR  = (const float*)d_in[7];
    const float* W_O   = (const float*)d_in[8];
    const float* qnw   = (const float*)d_in[9];
    const float* kvnw  = (const float*)d_in[10];
    float* out = (float*)d_out;   // fp32 output per reference dtype

    char* base = (char*)d_ws;
    size_t o = 0;
    auto alloc = [&](size_t bytes) {
        char* r = base + o;
        o += (bytes + 255) & ~(size_t)255;
        return r;
    };
    u16* WT1  = (u16*)alloc((size_t)1664 * 2048 * 2);
    u16* WT2  = (u16*)alloc((size_t)3072 * 1024 * 2);
    u16* WT3  = (u16*)alloc((size_t)4096 * 512 * 2);
    u16* WT_O = (u16*)alloc((size_t)2048 * 2048 * 2);
    u16* xb   = (u16*)alloc((size_t)M_ * 2048 * 2);    // x bf16; later Vt
    u16* U1   = (u16*)alloc((size_t)M_ * 2048 * 2);    // P1 then attn_out
    u16* P2   = (u16*)alloc((size_t)M_ * 3072 * 2);    // [qC | qR_raw]
    u16* P3   = (u16*)alloc((size_t)M_ * 4096 * 2);    // [kC | vC]
    u16* cQb  = (u16*)alloc((size_t)M_ * 1024 * 2);
    u16* cKVb = (u16*)alloc((size_t)M_ * 512 * 2);
    u16* qRb  = (u16*)alloc((size_t)M_ * 1024 * 2);    // (unused; layout kept)
    u16* kRb  = (u16*)alloc((size_t)M_ * 64 * 2);
    (void)qRb;
    u16* P1       = U1;
    u16* attn_out = U1;
    u16* Vt       = xb;

    // ---- dispatch 1: all 8 weight transposes + x cast
    TPack tp;
    const float* srcs[8] = {W_DQ, W_DKV, W_KR, W_UQ, W_QR, W_UK, W_UV, W_O};
    u16* dsts[8] = {WT1, WT1 + (size_t)1024*2048, WT1 + (size_t)1536*2048,
                    WT2, WT2 + (size_t)2048*1024,
                    WT3, WT3 + (size_t)2048*512, WT_O};
    const int Ks[8]   = {2048, 2048, 2048, 1024, 1024, 512, 512, 2048};
    const int Ns[8]   = {1024,  512,   64, 2048, 1024, 2048, 2048, 2048};
    const int ntxs[8] = {  32,   16,    4,   64,   32,   64,   64,   64};
    int cum = 0;
    for (int i = 0; i < 8; ++i) {
        tp.src[i] = srcs[i]; tp.dst[i] = dsts[i];
        tp.K[i] = Ks[i]; tp.N[i] = Ns[i]; tp.ntx[i] = ntxs[i];
        tp.start[i] = cum;
        cum += ntxs[i] * (Ks[i] / 32);
    }
    tp.start[8] = cum;   // 12544 transpose tiles
    const int ncast = (M_ * D_) / 1024;   // 8192 cast blocks
    prep_k<<<cum + ncast, 256, 0, stream>>>(tp, x, xb, cum);

    // ---- dispatch 2: proj1: x @ [W_DQ | W_DKV | W_KR] -> P1 (M x 1664)
    gemm_tn<1><<<dim3(1664/128, M_/128), 256, 0, stream>>>(xb, WT1, (void*)P1, 1664, 2048);

    // ---- dispatch 3: fused rmsnorm(q) + rmsnorm(kv) + rope_k
    normrope_k<<<dim3(M_, 3), 256, 0, stream>>>(P1, qnw, kvnw, cQb, cKVb, kRb);

    // ---- dispatch 4: proj2a: cQ @ [W_UQ|W_QR] -> P2 (128^2 structure)
    gemm_tn<1><<<dim3(3072/128, M_/128), 256, 0, stream>>>(cQb, WT2, (void*)P2, 3072, 1024);

    // ---- dispatch 5: proj2b: cKV @ [W_UK|W_UV] -> P3 (256^2 8-wave)
    gemm256_k<<<dim3(4096/256, M_/256), 512, 0, stream>>>(cKVb, WT3, P3, 4096, 512);

    // ---- dispatch 6: V^T transpose (RoPE-q fused into attn)
    vtrans_k<<<2048, 256, 0, stream>>>(P3, Vt);

    // ---- dispatch 7: attention — 512 thr/block; grid x=h (XCD), y=qb, z=b
    attn_mfma_k<<<dim3(H_, T_/ABQ, B_), 512, 0, stream>>>(P2, P3, kRb, Vt, attn_out);

    // ---- dispatch 8: output projection -> d_out (fp32)
    gemm_tn<0><<<dim3(2048/128, M_/128), 256, 0, stream>>>(attn_out, WT_O, (void*)out, 2048, 2048);
}

// Round 7
// 391.473 us; speedup vs baseline: 1.1257x; 1.0134x over previous
//
#include <hip/hip_runtime.h>
#include <cstdint>
#include <cstddef>

// ---------------- problem constants ----------------
#define B_   2
#define T_   2048
#define D_   2048
#define H_   16
#define DH_  128
#define DQ_  1024
#define DKV_ 512
#define DR_  64
#define M_   4096            // B_*T_
#define SCALE_ 0.07216878364870323f   // 1/sqrt(DH_+DR_)
#define SC2_   0.10412808709930322f   // SCALE_ * log2(e)
#define LN_BASE_ 13.122363377404328f  // ln(500000)

typedef unsigned short u16;
typedef __attribute__((ext_vector_type(8))) short short8;   // 8 bf16 (4 VGPRs)
typedef __attribute__((ext_vector_type(4))) float f32x4;    // 4 fp32 acc

__device__ __forceinline__ float b2f(u16 u) { return __uint_as_float(((uint32_t)u) << 16); }
__device__ __forceinline__ u16 f2b(float f) {            // RNE
    uint32_t x = __float_as_uint(f);
    return (u16)((x + 0x7fffu + ((x >> 16) & 1u)) >> 16);
}
__device__ __forceinline__ u16 f2b_fast(float f) {       // round-up-ties, 2 ops
    return (u16)((__float_as_uint(f) + 0x8000u) >> 16);
}

__device__ __forceinline__ void gload_lds16(const u16* src, u16* dst) {
    __builtin_amdgcn_global_load_lds(
        (const __attribute__((address_space(1))) uint32_t*)(uintptr_t)src,
        (__attribute__((address_space(3))) uint32_t*)(uintptr_t)dst, 16, 0, 0);
}

// ---- fused prep: 8 weight transposes (+cast) AND x fp32->bf16, one launch ---
struct TPack {
    const float* src[8];
    u16*         dst[8];
    int K[8];      // src rows
    int N[8];      // src cols (real)
    int ntx[8];    // tiles along out-row dim (covers padded N)
    int start[9];  // cumulative tile offsets
};

__global__ __launch_bounds__(256) void prep_k(TPack p, const float* __restrict__ x,
                                              u16* __restrict__ xb, int ntr) {
    const int bid = blockIdx.x;
    if (bid < ntr) {
        __shared__ float tile[32][33];
        int w = 0;
#pragma unroll
        for (int i = 1; i < 8; ++i) if (bid >= p.start[i]) w = i;
        const int lt = bid - p.start[w];
        const int bx = lt % p.ntx[w], by = lt / p.ntx[w];
        const float* in = p.src[w];
        u16* out = p.dst[w];
        const int K = p.K[w], N = p.N[w];
        const int k0 = by * 32, n0 = bx * 32;
        const int tx = threadIdx.x & 31, ty = threadIdx.x >> 5;  // 32x8
#pragma unroll
        for (int i = 0; i < 4; ++i) {
            int k = k0 + ty + i * 8;
            int n = n0 + tx;
            tile[ty + i * 8][tx] = (n < N) ? in[(size_t)k * N + n] : 0.f;
        }
        __syncthreads();
#pragma unroll
        for (int i = 0; i < 4; ++i) {
            int n = n0 + ty + i * 8;     // out row
            out[(size_t)n * K + k0 + tx] = f2b(tile[tx][ty + i * 8]);
        }
    } else {
        const int i = ((bid - ntr) * 256 + threadIdx.x) * 4;
        const float4 v = *(const float4*)(x + i);
        ushort4 o;
        o.x = f2b(v.x); o.y = f2b(v.y); o.z = f2b(v.z); o.w = f2b(v.w);
        *(ushort4*)(xb + i) = o;
    }
}

// ---------------- bf16 GEMM:  C(MxN) = A(MxK) @ B(KxN), Bt given as NxK ------
template <int OUT_BF16>
__global__ __launch_bounds__(256) void gemm_tn(const u16* __restrict__ A,
                                               const u16* __restrict__ Bt,
                                               void* __restrict__ Cv,
                                               int N, int K) {
    __shared__ __attribute__((aligned(16))) u16 lA[128 * 32];
    __shared__ __attribute__((aligned(16))) u16 lB[128 * 32];
    const int m0 = blockIdx.y * 128, n0 = blockIdx.x * 128;
    const int tid = threadIdx.x, wave = tid >> 6, lane = tid & 63;
    const int wm = (wave >> 1) * 64, wn = (wave & 1) * 64;
    const int r = lane & 15, kq = lane >> 4;

    f32x4 acc[4][4];
#pragma unroll
    for (int i = 0; i < 4; ++i)
#pragma unroll
        for (int j = 0; j < 4; ++j) acc[i][j] = (f32x4){0.f, 0.f, 0.f, 0.f};

    for (int kk = 0; kk < K; kk += 32) {
#pragma unroll
        for (int p = 0; p < 2; ++p) {
            const int c = p * 256 + wave * 64 + lane;          // 16B chunk id
            const u16* ga = A  + (size_t)(m0 + (c >> 2)) * K + kk + (c & 3) * 8;
            const u16* gb = Bt + (size_t)(n0 + (c >> 2)) * K + kk + (c & 3) * 8;
            u16* la = lA + (size_t)(p * 256 + wave * 64) * 8;  // wave-uniform base
            u16* lb = lB + (size_t)(p * 256 + wave * 64) * 8;
            gload_lds16(ga, la);
            gload_lds16(gb, lb);
        }
        __syncthreads();
        short8 av[4], bv[4];
#pragma unroll
        for (int mi = 0; mi < 4; ++mi)
            av[mi] = *(const short8*)&lA[(wm + mi * 16 + r) * 32 + kq * 8];
#pragma unroll
        for (int ni = 0; ni < 4; ++ni)
            bv[ni] = *(const short8*)&lB[(wn + ni * 16 + r) * 32 + kq * 8];
#pragma unroll
        for (int mi = 0; mi < 4; ++mi)
#pragma unroll
            for (int ni = 0; ni < 4; ++ni)
                acc[mi][ni] = __builtin_amdgcn_mfma_f32_16x16x32_bf16(
                    av[mi], bv[ni], acc[mi][ni], 0, 0, 0);
        __syncthreads();
    }
    const int r4 = (lane >> 4) * 4, cc = lane & 15;
#pragma unroll
    for (int mi = 0; mi < 4; ++mi)
#pragma unroll
        for (int ni = 0; ni < 4; ++ni)
#pragma unroll
            for (int i = 0; i < 4; ++i) {
                const int row = m0 + wm + mi * 16 + r4 + i;
                const int col = n0 + wn + ni * 16 + cc;
                const float v = acc[mi][ni][i];
                if (OUT_BF16) ((u16*)Cv)[(size_t)row * N + col] = f2b(v);
                else          ((float*)Cv)[(size_t)row * N + col] = v;
            }
}

// ================= 256x256 8-wave pipelined GEMM core (R5-verified) =========
// T2 chunk-XOR swizzle (source-preswizzled, linear LDS dest, swizzled read);
// T3/T4: 4 phases/K-tile, 2 staging loads/phase, counted vmcnt(2) once/tile.
#define S_BM 256
#define S_BN 256
#define S_BK 64

// macro-free core as a device function: fills acc[8][4] for this block's tile
__device__ __forceinline__ void gemm256_core(
    const u16* __restrict__ A, const u16* __restrict__ Bt, int K,
    int m0, int n0, int tid, f32x4 (&acc)[8][4],
    u16 (*sA)[S_BM * S_BK], u16 (*sB)[S_BN * S_BK]) {
    const int lane = tid & 63;
    const int wave = tid >> 6;
    const int wm = wave >> 2;                 // 2 x 4 wave grid
    const int r = lane & 15, kq = lane >> 4;
    const int wn = wave & 3;

    const u16* gA[4]; const u16* gB[4]; int dOf[4];
#pragma unroll
    for (int is = 0; is < 4; ++is) {
        const int c = is * 512 + tid;
        const int row = c >> 3, c16 = c & 7;
        gA[is] = A  + (size_t)(m0 + row) * K + ((c16 ^ (row & 7)) * 8);
        gB[is] = Bt + (size_t)(n0 + row) * K + ((c16 ^ (row & 7)) * 8);
        dOf[is] = c * 8;
    }

    const int NKT = K >> 6;

    auto STG = [&](int arr, int half, int bs, int kk) {
        u16* dst = arr ? (u16*)sB[bs] : (u16*)sA[bs];
        const u16** g = arr ? gB : gA;
#pragma unroll
        for (int is = half * 2; is < half * 2 + 2; ++is)
            gload_lds16(g[is] + kk, dst + dOf[is]);
    };

    STG(0, 0, 0, 0); STG(0, 1, 0, 0); STG(1, 0, 0, 0); STG(1, 1, 0, 0);

    short8 af[4][2], bf[2][2];
    for (int kt = 0; kt < NKT; ++kt) {
        const int cur = kt & 1;
        const int kk = (kt + 1) * 64;
        const int pf = (kt + 1 < NKT);
        const u16* cA = sA[cur];
        const u16* cB = sB[cur];

        auto lda = [&](int row, int g) -> short8 {
            return *(const short8*)&cA[row * 64 + ((g ^ (row & 7)) * 8)];
        };
        auto ldb = [&](int row, int g) -> short8 {
            return *(const short8*)&cB[row * 64 + ((g ^ (row & 7)) * 8)];
        };

#pragma unroll
        for (int ph = 0; ph < 4; ++ph) {
            const int mh = ph >> 1;
            const int nh = (ph == 1 || ph == 2) ? 1 : 0;
            if (pf) STG(ph >> 1, ph & 1, cur ^ 1, kk);
            if (ph == 0) {
                if (pf) asm volatile("s_waitcnt vmcnt(2)" ::: "memory");
                else    asm volatile("s_waitcnt vmcnt(0)" ::: "memory");
            }
            __builtin_amdgcn_s_barrier();
            asm volatile("" ::: "memory");
            if (!(ph & 1)) {
#pragma unroll
                for (int mi = 0; mi < 4; ++mi)
#pragma unroll
                    for (int ks = 0; ks < 2; ++ks)
                        af[mi][ks] = lda(wm * 128 + mh * 64 + mi * 16 + r, ks * 4 + kq);
            }
#pragma unroll
            for (int ni = 0; ni < 2; ++ni)
#pragma unroll
                for (int ks = 0; ks < 2; ++ks)
                    bf[ni][ks] = ldb(wn * 64 + nh * 32 + ni * 16 + r, ks * 4 + kq);
#pragma unroll
            for (int ks = 0; ks < 2; ++ks)
#pragma unroll
                for (int mi = 0; mi < 4; ++mi)
#pragma unroll
                    for (int ni = 0; ni < 2; ++ni)
                        acc[mh * 4 + mi][nh * 2 + ni] =
                            __builtin_amdgcn_mfma_f32_16x16x32_bf16(
                                af[mi][ks], bf[ni][ks],
                                acc[mh * 4 + mi][nh * 2 + ni], 0, 0, 0);
            asm volatile("" ::: "memory");
            __builtin_amdgcn_s_barrier();
            asm volatile("" ::: "memory");
        }
    }
}

// ---- proj2 merged: (cQ @ WT2 -> P2) + (cKV @ WT3 -> kC of P3, vC -> Vt^T) --
__global__ __launch_bounds__(512, 1) void gemm256p_k(
    const u16* __restrict__ A0, const u16* __restrict__ B0,
    u16* __restrict__ C0, int N0c, int K0,
    const u16* __restrict__ A1, const u16* __restrict__ B1,
    u16* __restrict__ C1, int N1c, int K1,
    u16* __restrict__ Vt, int vcol0, int nx0)
{
    __shared__ __attribute__((aligned(16))) u16 sA[2][S_BM * S_BK]; // 2x32 KB
    __shared__ __attribute__((aligned(16))) u16 sB[2][S_BN * S_BK]; // 2x32 KB
    const int sel = (int)blockIdx.x >= nx0;
    const u16* A  = sel ? A1 : A0;
    const u16* Bt = sel ? B1 : B0;
    const int  K  = sel ? K1 : K0;
    const int lbx = sel ? (blockIdx.x - nx0) : blockIdx.x;
    const int m0 = blockIdx.y * S_BM, n0 = lbx * S_BN;
    const int tid = threadIdx.x, lane = tid & 63;
    const int wave = tid >> 6, wm = wave >> 2, wn = wave & 3;
    const int kq = lane >> 4;

    f32x4 acc[8][4];
#pragma unroll
    for (int i = 0; i < 8; ++i)
#pragma unroll
        for (int j = 0; j < 4; ++j) acc[i][j] = (f32x4){0.f, 0.f, 0.f, 0.f};

    gemm256_core(A, Bt, K, m0, n0, tid, acc, sA, sB);

    const int r4c = kq * 4, cc = lane & 15;
    if (!sel) {
#pragma unroll
        for (int mf = 0; mf < 8; ++mf)
#pragma unroll
            for (int nf = 0; nf < 4; ++nf)
#pragma unroll
                for (int i = 0; i < 4; ++i) {
                    const int row = m0 + wm * 128 + mf * 16 + r4c + i;
                    const int col = n0 + wn * 64 + nf * 16 + cc;
                    C0[(size_t)row * N0c + col] = f2b(acc[mf][nf][i]);
                }
    } else if (n0 < vcol0) {   // kC region -> P3 (stride N1c)
#pragma unroll
        for (int mf = 0; mf < 8; ++mf)
#pragma unroll
            for (int nf = 0; nf < 4; ++nf)
#pragma unroll
                for (int i = 0; i < 4; ++i) {
                    const int row = m0 + wm * 128 + mf * 16 + r4c + i;
                    const int col = n0 + wn * 64 + nf * 16 + cc;
                    C1[(size_t)row * N1c + col] = f2b(acc[mf][nf][i]);
                }
    } else {                   // vC region -> Vt DIRECT TRANSPOSED (b,c,t)
#pragma unroll
        for (int mf = 0; mf < 8; ++mf)
#pragma unroll
            for (int nf = 0; nf < 4; ++nf) {
                const int tp = m0 + wm * 128 + mf * 16 + r4c;        // t' base
                const int c  = n0 - vcol0 + wn * 64 + nf * 16 + cc;  // dv dim
                u16 tmp[4];
#pragma unroll
                for (int i = 0; i < 4; ++i) tmp[i] = f2b(acc[mf][nf][i]);
                *(ushort4*)&Vt[((size_t)((tp >> 11) * 2048 + c)) * 2048 + (tp & 2047)]
                    = *(ushort4*)tmp;
            }
    }
}

// ---- WO: attn_out @ WT_O -> out (fp32), K=2048 deep pipeline ---------------
__global__ __launch_bounds__(512, 1) void gemm256o_k(
    const u16* __restrict__ A, const u16* __restrict__ Bt,
    float* __restrict__ Cf, int N, int K)
{
    __shared__ __attribute__((aligned(16))) u16 sA[2][S_BM * S_BK];
    __shared__ __attribute__((aligned(16))) u16 sB[2][S_BN * S_BK];
    const int m0 = blockIdx.y * S_BM, n0 = blockIdx.x * S_BN;
    const int tid = threadIdx.x, lane = tid & 63;
    const int wave = tid >> 6, wm = wave >> 2, wn = wave & 3;
    const int kq = lane >> 4;

    f32x4 acc[8][4];
#pragma unroll
    for (int i = 0; i < 8; ++i)
#pragma unroll
        for (int j = 0; j < 4; ++j) acc[i][j] = (f32x4){0.f, 0.f, 0.f, 0.f};

    gemm256_core(A, Bt, K, m0, n0, tid, acc, sA, sB);

    const int r4c = kq * 4, cc = lane & 15;
#pragma unroll
    for (int mf = 0; mf < 8; ++mf)
#pragma unroll
        for (int nf = 0; nf < 4; ++nf)
#pragma unroll
            for (int i = 0; i < 4; ++i) {
                const int row = m0 + wm * 128 + mf * 16 + r4c + i;
                const int col = n0 + wn * 64 + nf * 16 + cc;
                Cf[(size_t)row * N + col] = acc[mf][nf][i];
            }
}

// ---- fused per-row ops on P1: rmsnorm(q), rmsnorm(kv), rope_k — one launch --
__global__ __launch_bounds__(256) void normrope_k(const u16* __restrict__ P1,
                                                  const float* __restrict__ qnw,
                                                  const float* __restrict__ kvnw,
                                                  u16* __restrict__ cQb,
                                                  u16* __restrict__ cKVb,
                                                  u16* __restrict__ kRb) {
    const int which = blockIdx.y;
    if (which < 2) {
        const int row = blockIdx.x;
        const int N = which ? 512 : 1024;
        const int off = which ? 1024 : 0;
        const float* w = which ? kvnw : qnw;
        u16* outp = which ? cKVb : cQb;
        const u16* src = P1 + (size_t)row * 1664 + off;
        const int j = threadIdx.x * 4;
        float v[4] = {0.f, 0.f, 0.f, 0.f};
        if (j < N) {
            ushort4 u = *(const ushort4*)(src + j);
            v[0] = b2f(u.x); v[1] = b2f(u.y); v[2] = b2f(u.z); v[3] = b2f(u.w);
        }
        float ss = v[0]*v[0] + v[1]*v[1] + v[2]*v[2] + v[3]*v[3];
#pragma unroll
        for (int offc = 32; offc; offc >>= 1) ss += __shfl_down(ss, offc);
        __shared__ float red[4];
        const int wave = threadIdx.x >> 6, lane = threadIdx.x & 63;
        if (lane == 0) red[wave] = ss;
        __syncthreads();
        const float tot = red[0] + red[1] + red[2] + red[3];
        const float sc = rsqrtf(tot / (float)N + 1e-6f);
        if (j < N) {
            ushort4 o;
            o.x = f2b(v[0] * sc * w[j]);
            o.y = f2b(v[1] * sc * w[j + 1]);
            o.z = f2b(v[2] * sc * w[j + 2]);
            o.w = f2b(v[3] * sc * w[j + 3]);
            *(ushort4*)(outp + (size_t)row * N + j) = o;
        }
    } else {
        // rope_k: 4 rows per block, 64 lanes each
        if (blockIdx.x >= 1024) return;
        const int row = blockIdx.x * 4 + (threadIdx.x >> 6);
        const int j = threadIdx.x & 63;
        const int t = row & (T_ - 1);
        const int i = j & 31;
        const float invf = __expf(-LN_BASE_ * (float)(2 * i) * (1.0f / 64.0f));
        const float ang = (float)t * invf;
        const float c = cosf(ang), s = sinf(ang);
        const u16* src = P1 + (size_t)row * 1664 + 1536;
        const float v = b2f(src[j]);
        const float rot = (j < 32) ? -b2f(src[j + 32]) : b2f(src[j - 32]);
        kRb[(size_t)row * 64 + j] = f2b(v * c + rot * s);
    }
}

// ---------------- MFMA flash attention (causal, d=192, dv=128) --------------
// R6 structure FROZEN (proven 93.4us): 3-buffer, depth-2 prefetch, ONE
// barrier per K-tile, counted vmcnt(6); RoPE(q) fused at Q-load.
#define ABQ  128
#define ABK  64
#define NW   8
#define KSTR 200   // sK row stride u16 (25 chunks x 8)
#define VSTR 72    // sV row stride u16 (9 chunks x 8)
#define PSTR 72    // sP row stride u16
#define VOFF 12800 // u16 offset of V region inside a KV buffer (25*512)
#define KVSZ 22016 // u16 per KV buffer (43*512)
#define QSTRIDE 3072   // P2 row stride (qC cols 0..2047, qR_raw 2048..3071)
#define KSTRIDE 4096   // P3 row stride (kC cols 0..2047)

__global__ __launch_bounds__(512, 1) void attn_mfma_k(
    const u16* __restrict__ qC,
    const u16* __restrict__ kC, const u16* __restrict__ kR,
    const u16* __restrict__ Vt, u16* __restrict__ outp)
{
    __shared__ __attribute__((aligned(16))) u16 sKV[3][KVSZ];   // 3 x 43 KB = 129 KB
    __shared__ __attribute__((aligned(16))) u16 sP[NW * 16 * PSTR]; // 18 KB

    const int h = blockIdx.x, b = blockIdx.z;                      // x=h: XCD cluster
    const int qb = b ? (15 - (int)blockIdx.y) : (int)blockIdx.y;   // causal balance
    const int q0 = qb * ABQ;
    const int tid = threadIdx.x, wave = tid >> 6, lane = tid & 63;
    const int r = lane & 15, kq = lane >> 4, r4 = kq * 4;
    const int wq = wave * 16;

    // ---- per-wave staging plan: 6 slots each, precomputed bases
    const u16* gsrc[6]; int gstep[6]; int doff[6];
#pragma unroll
    for (int j = 0; j < 6; ++j) {
        const int i = wave + NW * j;              // 0..47
        const int slot = (i < 43) ? i : (i - 43); // pad slots dup K slots 0..4
        if (slot < 25) {                          // K chunk
            const int s = slot * 64 + lane;
            const int rr2 = s / 25;
            int cc = s - rr2 * 25;
            if (cc > 23) cc = 0;                  // pad col: harmless dup
            if (cc < 16) {
                gsrc[j] = kC + (size_t)(b * T_ + rr2) * KSTRIDE + h * 128 + cc * 8;
                gstep[j] = ABK * KSTRIDE;
            } else {
                gsrc[j] = kR + (size_t)(b * T_ + rr2) * 64 + (cc - 16) * 8;
                gstep[j] = ABK * 64;
            }
            doff[j] = slot * 512;
        } else {                                  // V chunk
            const int sl = slot - 25;             // 0..17
            const int s = sl * 64 + lane;
            const int rr2 = s / 9;
            int cc = s - rr2 * 9;
            if (cc > 7) cc = 0;                   // pad col
            gsrc[j] = Vt + ((size_t)(b * H_ + h) * 128 + rr2) * T_ + cc * 8;
            gstep[j] = ABK;
            doff[j] = VOFF + sl * 512;
        }
    }

    // ---- Q fragments in registers; RoPE(q) fused for the rope dims
    short8 qf[6];
    {
        const int t = q0 + wq + r;
        const u16* qcrow = qC + (size_t)(b * T_ + t) * QSTRIDE + h * 128 + kq * 8;
#pragma unroll
        for (int kc = 0; kc < 4; ++kc) qf[kc] = *(const short8*)(qcrow + kc * 32);
        const u16* qrraw = qC + (size_t)(b * T_ + t) * QSTRIDE + 2048 + h * 64 + kq * 8;
        const short8 q0v = *(const short8*)(qrraw);
        const short8 q1v = *(const short8*)(qrraw + 32);
        short8 o0, o1;
#pragma unroll
        for (int j = 0; j < 8; ++j) {
            const int i = kq * 8 + j;             // dim mod 32 (same for both halves)
            const float invf = __expf(-LN_BASE_ * (float)(2 * i) * (1.0f / 64.0f));
            const float ang = (float)t * invf;
            const float cs = cosf(ang), sn = sinf(ang);
            const float a = b2f((u16)q0v[j]), bb = b2f((u16)q1v[j]);
            o0[j] = (short)f2b(a * cs - bb * sn);
            o1[j] = (short)f2b(bb * cs + a * sn);
        }
        qf[4] = o0; qf[5] = o1;
    }

    f32x4 Oa[8];
#pragma unroll
    for (int nt = 0; nt < 8; ++nt) Oa[nt] = (f32x4){0.f, 0.f, 0.f, 0.f};
    float Lrow[4] = {0.f, 0.f, 0.f, 0.f};

    u16* myP = sP + wave * 16 * PSTR;

    auto STAGE = [&](int kt2, int bs) {
        u16* dst = &sKV[bs][0];
#pragma unroll
        for (int j = 0; j < 6; ++j)
            gload_lds16(gsrc[j] + (size_t)kt2 * (size_t)gstep[j], dst + doff[j]);
    };

    const int nkt = 2 * qb + 2;   // >= 2 always
    STAGE(0, 0);
    STAGE(1, 1);
    for (int kt = 0; kt < nkt; ++kt) {
        const int cur = kt % 3;
        // acquire: tile kt's 6 loads are the oldest outstanding
        if (kt == 0 || kt >= nkt - 1) {
            asm volatile("s_waitcnt vmcnt(0)" ::: "memory");
        } else {
            asm volatile("s_waitcnt vmcnt(6)" ::: "memory");
        }
        __builtin_amdgcn_s_barrier();
        asm volatile("" ::: "memory");

        const u16* cK = &sKV[cur][0];
        const u16* cV = &sKV[cur][VOFF];
        const int k0 = kt * ABK;

        // ---- S = Q K^T  (24 MFMA/wave)
        f32x4 Sa[4];
#pragma unroll
        for (int nt = 0; nt < 4; ++nt) Sa[nt] = (f32x4){0.f, 0.f, 0.f, 0.f};
#pragma unroll
        for (int kc = 0; kc < 6; ++kc) {
            short8 kf[4];
#pragma unroll
            for (int nt = 0; nt < 4; ++nt)
                kf[nt] = *(const short8*)&cK[(nt * 16 + r) * KSTR + (kc * 4 + kq) * 8];
#pragma unroll
            for (int nt = 0; nt < 4; ++nt)
                Sa[nt] = __builtin_amdgcn_mfma_f32_16x16x32_bf16(
                    qf[kc], kf[nt], Sa[nt], 0, 0, 0);
        }

        // ---- no-max softmax: p = exp2(S*SC2); wave-uniform mask split
        if (kt < nkt - 2) {
#pragma unroll
            for (int i = 0; i < 4; ++i) {
                float sm = 0.f;
#pragma unroll
                for (int nt = 0; nt < 4; ++nt) {
                    const float p = exp2f(Sa[nt][i] * SC2_);
                    sm += p;
                    myP[(r4 + i) * PSTR + nt * 16 + r] = f2b_fast(p);
                }
                Lrow[i] += sm;
            }
        } else {
#pragma unroll
            for (int i = 0; i < 4; ++i) {
                const int grow = q0 + wq + r4 + i;
                float sm = 0.f;
#pragma unroll
                for (int nt = 0; nt < 4; ++nt) {
                    float p = exp2f(Sa[nt][i] * SC2_);
                    p = (k0 + nt * 16 + r > grow) ? 0.f : p;
                    sm += p;
                    myP[(r4 + i) * PSTR + nt * 16 + r] = f2b_fast(p);
                }
                Lrow[i] += sm;
            }
        }

        // ---- O += P V  (P wave-local; same-wave DS order via lgkmcnt)
#pragma unroll
        for (int kc2 = 0; kc2 < 2; ++kc2) {
            const short8 pf = *(const short8*)&myP[r * PSTR + (kc2 * 4 + kq) * 8];
#pragma unroll
            for (int nt = 0; nt < 8; ++nt) {
                const short8 vf = *(const short8*)&cV[(nt * 16 + r) * VSTR + (kc2 * 4 + kq) * 8];
                Oa[nt] = __builtin_amdgcn_mfma_f32_16x16x32_bf16(
                    pf, vf, Oa[nt], 0, 0, 0);
            }
        }

        // ---- prefetch depth 2: stage tile kt+2 into buf[(kt+2)%3].
        if (kt + 2 < nkt) STAGE(kt + 2, (kt + 2) % 3);
    }

    // ---- epilogue: reduce L across the 16 lanes of each quad-group, O /= L
#pragma unroll
    for (int i = 0; i < 4; ++i) {
        float L = Lrow[i];
        L += __shfl_xor(L, 1);
        L += __shfl_xor(L, 2);
        L += __shfl_xor(L, 4);
        L += __shfl_xor(L, 8);
        const float inv = 1.0f / L;
        const int t = q0 + wq + r4 + i;
        u16* orow = outp + (size_t)(b * T_ + t) * 2048 + h * 128;
#pragma unroll
        for (int nt = 0; nt < 8; ++nt)
            orow[nt * 16 + r] = f2b(Oa[nt][i] * inv);
    }
}

// ---------------- host side -------------------------------------------------
// Workspace plan: 139.46 MB (proven safe). U1 time-shared: P1 then attn_out.
// Vt reuses xb. 6 dispatches: prep -> proj1 -> normrope ->
// proj2merged(256^2, vC->Vt direct) -> attn -> WO(256^2 fp32)
extern "C" void kernel_launch(void* const* d_in, const int* in_sizes, int n_in,
                              void* d_out, int out_size, void* d_ws, size_t ws_size,
                              hipStream_t stream) {
    (void)in_sizes; (void)n_in; (void)out_size; (void)ws_size;
    const float* x     = (const float*)d_in[0];
    const float* W_DQ  = (const float*)d_in[1];
    const float* W_UQ  = (const float*)d_in[2];
    const float* W_QR  = (const float*)d_in[3];
    const float* W_DKV = (const float*)d_in[4];
    const float* W_UK  = (const float*)d_in[5];
    const float* W_UV  = (const float*)d_in[6];
    const float* W_KR  = (const float*)d_in[7];
    const float* W_O   = (const float*)d_in[8];
    const float* qnw   = (const float*)d_in[9];
    const float* kvnw  = (const float*)d_in[10];
    float* out = (float*)d_out;   // fp32 output per reference dtype

    char* base = (char*)d_ws;
    size_t o = 0;
    auto alloc = [&](size_t bytes) {
        char* r = base + o;
        o += (bytes + 255) & ~(size_t)255;
        return r;
    };
    u16* WT1  = (u16*)alloc((size_t)1664 * 2048 * 2);
    u16* WT2  = (u16*)alloc((size_t)3072 * 1024 * 2);
    u16* WT3  = (u16*)alloc((size_t)4096 * 512 * 2);
    u16* WT_O = (u16*)alloc((size_t)2048 * 2048 * 2);
    u16* xb   = (u16*)alloc((size_t)M_ * 2048 * 2);    // x bf16; later Vt
    u16* U1   = (u16*)alloc((size_t)M_ * 2048 * 2);    // P1 then attn_out
    u16* P2   = (u16*)alloc((size_t)M_ * 3072 * 2);    // [qC | qR_raw]
    u16* P3   = (u16*)alloc((size_t)M_ * 4096 * 2);    // [kC | (unused)]
    u16* cQb  = (u16*)alloc((size_t)M_ * 1024 * 2);
    u16* cKVb = (u16*)alloc((size_t)M_ * 512 * 2);
    u16* qRb  = (u16*)alloc((size_t)M_ * 1024 * 2);    // (unused; layout kept)
    u16* kRb  = (u16*)alloc((size_t)M_ * 64 * 2);
    (void)qRb;
    u16* P1       = U1;
    u16* attn_out = U1;
    u16* Vt       = xb;

    // ---- dispatch 1: all 8 weight transposes + x cast
    TPack tp;
    const float* srcs[8] = {W_DQ, W_DKV, W_KR, W_UQ, W_QR, W_UK, W_UV, W_O};
    u16* dsts[8] = {WT1, WT1 + (size_t)1024*2048, WT1 + (size_t)1536*2048,
                    WT2, WT2 + (size_t)2048*1024,
                    WT3, WT3 + (size_t)2048*512, WT_O};
    const int Ks[8]   = {2048, 2048, 2048, 1024, 1024, 512, 512, 2048};
    const int Ns[8]   = {1024,  512,   64, 2048, 1024, 2048, 2048, 2048};
    const int ntxs[8] = {  32,   16,    4,   64,   32,   64,   64,   64};
    int cum = 0;
    for (int i = 0; i < 8; ++i) {
        tp.src[i] = srcs[i]; tp.dst[i] = dsts[i];
        tp.K[i] = Ks[i]; tp.N[i] = Ns[i]; tp.ntx[i] = ntxs[i];
        tp.start[i] = cum;
        cum += ntxs[i] * (Ks[i] / 32);
    }
    tp.start[8] = cum;   // 12544 transpose tiles
    const int ncast = (M_ * D_) / 1024;   // 8192 cast blocks
    prep_k<<<cum + ncast, 256, 0, stream>>>(tp, x, xb, cum);

    // ---- dispatch 2: proj1: x @ [W_DQ | W_DKV | W_KR] -> P1 (M x 1664)
    gemm_tn<1><<<dim3(1664/128, M_/128), 256, 0, stream>>>(xb, WT1, (void*)P1, 1664, 2048);

    // ---- dispatch 3: fused rmsnorm(q) + rmsnorm(kv) + rope_k
    normrope_k<<<dim3(M_, 3), 256, 0, stream>>>(P1, qnw, kvnw, cQb, cKVb, kRb);

    // ---- dispatch 4: proj2 MERGED (256^2 pipelined):
    //   blocks [0,12): cQ @ WT2 -> P2 (N=3072)
    //   blocks [12,28): cKV @ WT3 -> cols<2048 to P3 (kC), cols>=2048 to Vt^T
    gemm256p_k<<<dim3(3072/256 + 4096/256, M_/256), 512, 0, stream>>>(
        cQb,  WT2, P2, 3072, 1024,
        cKVb, WT3, P3, 4096, 512,
        Vt, 2048, 3072/256);

    // ---- dispatch 5: attention — 512 thr/block; grid x=h (XCD), y=qb, z=b
    attn_mfma_k<<<dim3(H_, T_/ABQ, B_), 512, 0, stream>>>(P2, P3, kRb, Vt, attn_out);

    // ---- dispatch 6: output projection (256^2 pipelined, fp32 out)
    gemm256o_k<<<dim3(2048/256, M_/256), 512, 0, stream>>>(attn_out, WT_O, out, 2048, 2048);
}